// Round 3
// baseline (383.226 us; speedup 1.0000x reference)
//
#include <hip/hip_runtime.h>
#include <cstdint>

#define T_STEPS 16384

// ---- workspace float offsets ----
#define WS_U     0        // 256
#define WS_V     256      // 256
#define WS_W1ZT  512      // 2048 [c][k] 8x256
#define WS_PEN   2560     // 64
#define WS_A     2624     // 64
#define WS_W4T   2688     // 512 [i][z] 64x8
#define WS_W2C   3200     // 32768 [jc][k][jj] 4x256x32
#define WS_W3T   35968    // 8192 [j][i] 128x64
#define WS_DV    44160    // 131072 (16384x8)
#define WS_G     175232   // 131072 (16384x8)
#define WS_CONS  306304   // 1048576 (16384x8x8)
#define WS_END_F 1354880
// byte offsets after float region
#define WSB_NXT8 (WS_END_F * 4)          // 131072 bytes (u8 nxt[t][c])
#define WSB_CUR  (WSB_NXT8 + 131072)     // 65536 bytes (u32 cur[t])

__device__ __forceinline__ unsigned int fn_compose(unsigned int hi, unsigned int lo) {
  unsigned int r = 0;
  #pragma unroll
  for (int x = 0; x < 8; ++x) {
    unsigned int m = (lo >> (3 * x)) & 7u;
    r |= ((hi >> (3 * m)) & 7u) << (3 * x);
  }
  return r;
}

// ---------------- one merged prep launch: transposes + gumbel + setup + diversity ----------------
__global__ void __launch_bounds__(256) k_prepAll(
    const float* __restrict__ pa, const float* __restrict__ times,
    const float* __restrict__ gum, const int* __restrict__ edge,
    const float* __restrict__ W1, const float* __restrict__ b1,
    const float* __restrict__ W2, const float* __restrict__ W3,
    const float* __restrict__ W4,
    const float* __restrict__ D1, const float* __restrict__ d1,
    const float* __restrict__ D2, const float* __restrict__ d2,
    const float* __restrict__ D3, const float* __restrict__ d3,
    float* __restrict__ ws) {
  int b = blockIdx.x, tid = threadIdx.x;
  if (b < 128) {            // W2C: chunk-contiguous relayout of W2
    int e = b * 256 + tid;  // < 32768
    int jj = e & 31, k = (e >> 5) & 255, jc = e >> 13;
    ws[WS_W2C + e] = W2[(jc * 32 + jj) * 256 + k];
  } else if (b < 160) {     // W3T[j][i] = W3[i][j]
    int e = (b - 128) * 256 + tid;  // < 8192
    int i = e & 63, j = e >> 6;
    ws[WS_W3T + e] = W3[i * 128 + j];
  } else if (b < 672) {     // gumbels
    int e = (b - 160) * 256 + tid;  // < 131072
    float uu = gum[e];
    ws[WS_G + e] = -logf(-logf(uu + 1e-20f) + 1e-20f);
  } else if (b == 672) {    // setup: U, V, W1ZT, W4T, PEN
    {
      int k = tid;
      float acc = b1[k];
      #pragma unroll
      for (int i = 0; i < 8; ++i) acc = fmaf(pa[i], W1[k * 17 + i], acc);
      ws[WS_U + k] = acc;
      ws[WS_V + k] = W1[k * 17 + 8];
    }
    for (int e = tid; e < 2048; e += 256) {
      int cc = e >> 8, k = e & 255;
      ws[WS_W1ZT + e] = W1[k * 17 + 9 + cc];
    }
    for (int e = tid; e < 512; e += 256) {
      int k = e >> 3, z = e & 7;
      ws[WS_W4T + e] = W4[z * 64 + k];
    }
    if (tid < 64) ws[WS_A + tid] = ((tid >> 3) == (tid & 7)) ? 1.0f : 0.0f;
    __syncthreads();
    if (tid == 0) {
      for (int e = 0; e < 16; ++e) {
        int aa = edge[e], bb = edge[16 + e];
        ws[WS_A + aa * 8 + bb] = 1.0f;
        ws[WS_A + bb * 8 + aa] = 1.0f;
      }
    }
    __syncthreads();
    if (tid < 64) ws[WS_PEN + tid] = 1000.0f * (1.0f - ws[WS_A + tid]);
  } else {                  // diversity: blocks 673..736, thread = t, all-register
    int t = (b - 673) * 256 + tid;
    float last = times[T_STEPS - 1];
    float st = (last > 0.0f) ? times[t] / last : 0.0f;
    float h1d[128];
    #pragma unroll
    for (int k = 0; k < 128; ++k) {
      float a = d1[k];
      #pragma unroll
      for (int i2 = 0; i2 < 8; ++i2) a = fmaf(pa[i2], D1[k * 9 + i2], a);
      h1d[k] = fmaxf(fmaf(st, D1[k * 9 + 8], a), 0.0f);
    }
    float dva[8];
    #pragma unroll
    for (int z = 0; z < 8; ++z) dva[z] = d3[z];
    for (int i = 0; i < 64; ++i) {
      float a = d2[i];
      #pragma unroll
      for (int k = 0; k < 128; ++k) a = fmaf(D2[i * 128 + k], h1d[k], a);
      float h2 = fmaxf(a, 0.0f);
      #pragma unroll
      for (int z = 0; z < 8; ++z) dva[z] = fmaf(D3[z * 64 + i], h2, dva[z]);
    }
    #pragma unroll
    for (int z = 0; z < 8; ++z) ws[WS_DV + t * 8 + z] = tanhf(dva[z]);
  }
}

// ---------------- phase B: wave=c, lane=t; all-register, zero LDS, zero barriers ----------------
__global__ void __launch_bounds__(512, 2) k_phaseB(
    const float* __restrict__ times,
    const float* __restrict__ u_, const float* __restrict__ v_,
    const float* __restrict__ w1zt, const float* __restrict__ w2c,
    const float* __restrict__ w3t, const float* __restrict__ w4t,
    const float* __restrict__ b2, const float* __restrict__ b3,
    const float* __restrict__ b4,
    const float* __restrict__ dv, const float* __restrict__ gt,
    const float* __restrict__ pen, const float* __restrict__ tau,
    float* __restrict__ cons_out, unsigned char* __restrict__ nxt_out) {
  int tid = threadIdx.x;
  int lane = tid & 63;
  int c = __builtin_amdgcn_readfirstlane(tid >> 6);
  int t = blockIdx.x * 64 + lane;
  float last = times[T_STEPS - 1];
  float st = (last > 0.0f) ? times[t] / last : 0.0f;
  const float* w1c = w1zt + c * 256;

  float acc3[64];
  #pragma unroll
  for (int i = 0; i < 64; ++i) acc3[i] = b3[i];

  for (int jc = 0; jc < 4; ++jc) {
    const float* wc = w2c + jc * 8192;   // chunk-contiguous weight stream
    const float* bb = b2 + jc * 32;
    const float* w3 = w3t + jc * 32 * 64;
    float acc2[32];
    #pragma unroll
    for (int jj = 0; jj < 32; ++jj) acc2[jj] = bb[jj];
    #pragma unroll 2
    for (int k = 0; k < 256; ++k) {
      float h = fmaxf(fmaf(st, v_[k], u_[k]) + w1c[k], 0.0f);
      #pragma unroll
      for (int jj = 0; jj < 32; ++jj)
        acc2[jj] = fmaf(wc[k * 32 + jj], h, acc2[jj]);
    }
    // partial layer 3 over this j-chunk (h2 chunk dies here)
    #pragma unroll
    for (int jj = 0; jj < 32; ++jj) {
      float h2 = fmaxf(acc2[jj], 0.0f);
      #pragma unroll
      for (int i = 0; i < 64; ++i)
        acc3[i] = fmaf(w3[jj * 64 + i], h2, acc3[i]);
    }
  }

  // layer 4
  float a4[8];
  #pragma unroll
  for (int z = 0; z < 8; ++z) a4[z] = b4[z];
  #pragma unroll 4
  for (int i = 0; i < 64; ++i) {
    float h3 = fmaxf(acc3[i], 0.0f);
    #pragma unroll
    for (int z = 0; z < 8; ++z) a4[z] = fmaf(w4t[i * 8 + z], h3, a4[z]);
  }

  // epilogue: in-lane; argmax with first-index tie-break
  float4 dv0 = *(const float4*)(dv + (size_t)t * 8);
  float4 dv1 = *(const float4*)(dv + (size_t)t * 8 + 4);
  float4 g0  = *(const float4*)(gt + (size_t)t * 8);
  float4 g1  = *(const float4*)(gt + (size_t)t * 8 + 4);
  float dvv[8] = {dv0.x, dv0.y, dv0.z, dv0.w, dv1.x, dv1.y, dv1.z, dv1.w};
  float gv[8]  = {g0.x, g0.y, g0.z, g0.w, g1.x, g1.y, g1.z, g1.w};
  float sgn = (tau[0] > 0.0f) ? 1.0f : -1.0f;  // argmax((x)/tau) order
  float cons[8];
  float best = 0.0f; int bz = 0;
  #pragma unroll
  for (int z = 0; z < 8; ++z) {
    float lg = fmaf(0.2f, dvv[z], a4[z]) - pen[c * 8 + z];
    cons[z] = lg;
    float yv = (lg + gv[z]) * sgn;
    if (z == 0) { best = yv; bz = 0; }
    else if (yv > best) { best = yv; bz = z; }
  }
  float* co = cons_out + ((size_t)t * 8 + c) * 8;
  *(float4*)co = make_float4(cons[0], cons[1], cons[2], cons[3]);
  *(float4*)(co + 4) = make_float4(cons[4], cons[5], cons[6], cons[7]);
  nxt_out[t * 8 + c] = (unsigned char)bz;
}

// ---------------- phase C: parallel prefix over transition functions ----------------
__global__ void __launch_bounds__(256) k_phaseC(float* __restrict__ ws, float* __restrict__ d_out) {
  int tid = threadIdx.x;
  const unsigned char* nxt8 = (const unsigned char*)ws + WSB_NXT8;
  unsigned int* cur_arr = (unsigned int*)((char*)ws + WSB_CUR);
  const unsigned int IDENT = 0x00FAC688u;
  unsigned int f[64];
  int t0 = tid * 64;
  unsigned int F = IDENT;
  #pragma unroll
  for (int i = 0; i < 64; ++i) {
    uint2 b = *(const uint2*)(nxt8 + (size_t)(t0 + i) * 8);
    unsigned int fn = 0;
    #pragma unroll
    for (int q = 0; q < 4; ++q) fn |= ((b.x >> (8 * q)) & 7u) << (3 * q);
    #pragma unroll
    for (int q = 0; q < 4; ++q) fn |= ((b.y >> (8 * q)) & 7u) << (3 * (q + 4));
    f[i] = fn;
    F = fn_compose(fn, F);
  }
  __shared__ unsigned int sc[256];
  sc[tid] = F;
  __syncthreads();
  #pragma unroll
  for (int d = 1; d < 256; d <<= 1) {
    unsigned int v = sc[tid];
    unsigned int p = (tid >= d) ? sc[tid - d] : 0u;
    unsigned int nv = (tid >= d) ? fn_compose(v, p) : v;
    __syncthreads();
    sc[tid] = nv;
    __syncthreads();
  }
  unsigned int E = (tid == 0) ? IDENT : sc[tid - 1];
  unsigned int state = E & 7u;
  #pragma unroll
  for (int i = 0; i < 64; ++i) {
    int tt = t0 + i;
    cur_arr[tt] = state;
    unsigned int nx = (f[i] >> (3 * state)) & 7u;
    d_out[131072 + tt] = (float)nx;
    state = nx;
  }
}

// ---------------- gather ----------------
__global__ void k_gather(const float* __restrict__ ws, float* __restrict__ d_out) {
  int idx = blockIdx.x * 256 + threadIdx.x;  // < 131072
  const unsigned int* cur_arr = (const unsigned int*)((const char*)ws + WSB_CUR);
  int t = idx >> 3, z = idx & 7;
  unsigned int cur = cur_arr[t];
  d_out[idx] = ws[WS_CONS + (t * 8 + (int)cur) * 8 + z];
}

extern "C" void kernel_launch(void* const* d_in, const int* in_sizes, int n_in,
                              void* d_out, int out_size, void* d_ws, size_t ws_size,
                              hipStream_t stream) {
  const float* pa    = (const float*)d_in[0];
  const float* times = (const float*)d_in[1];
  const float* gum   = (const float*)d_in[2];
  const int*   edge  = (const int*)d_in[3];
  const float* W1  = (const float*)d_in[4];
  const float* b1  = (const float*)d_in[5];
  const float* W2  = (const float*)d_in[6];
  const float* b2  = (const float*)d_in[7];
  const float* W3  = (const float*)d_in[8];
  const float* b3  = (const float*)d_in[9];
  const float* W4  = (const float*)d_in[10];
  const float* b4  = (const float*)d_in[11];
  const float* D1  = (const float*)d_in[12];
  const float* d1v = (const float*)d_in[13];
  const float* D2  = (const float*)d_in[14];
  const float* d2v = (const float*)d_in[15];
  const float* D3  = (const float*)d_in[16];
  const float* d3v = (const float*)d_in[17];
  const float* tau = (const float*)d_in[18];
  float* ws = (float*)d_ws;
  float* out = (float*)d_out;

  k_prepAll<<<737, 256, 0, stream>>>(pa, times, gum, edge, W1, b1, W2, W3, W4,
                                     D1, d1v, D2, d2v, D3, d3v, ws);
  k_phaseB<<<256, 512, 0, stream>>>(times,
                                    ws + WS_U, ws + WS_V, ws + WS_W1ZT, ws + WS_W2C,
                                    ws + WS_W3T, ws + WS_W4T, b2, b3, b4,
                                    ws + WS_DV, ws + WS_G, ws + WS_PEN, tau,
                                    ws + WS_CONS, (unsigned char*)ws + WSB_NXT8);
  k_phaseC<<<1, 256, 0, stream>>>(ws, out);
  k_gather<<<512, 256, 0, stream>>>(ws, out);
}

// Round 4
// 367.453 us; speedup vs baseline: 1.0429x; 1.0429x over previous
//
#include <hip/hip_runtime.h>
#include <cstdint>

#define T_STEPS 16384

// ---- workspace float offsets ----
#define WS_U     0        // 256
#define WS_V     256      // 256
#define WS_W1ZT  512      // 2048 [c][k] 8x256
#define WS_PEN   2560     // 64
#define WS_A     2624     // 64
#define WS_W4T   2688     // 512 [i][z] 64x8
#define WS_W2C   3200     // 32768 [jc][k][jj] 4x256x32
#define WS_W3T   35968    // 8192 [j][i] 128x64
#define WS_DV    44160    // 131072 (16384x8)
#define WS_G     175232   // 131072 (16384x8)
#define WS_CONS  306304   // 1048576 (16384x8x8)
#define WS_END_F 1354880
// byte offsets after float region
#define WSB_NXT8 ((size_t)WS_END_F * 4)      // 131072 bytes (u8 nxt[t][c])
#define WSB_CUR  (WSB_NXT8 + 131072)         // 65536 bytes (u32 cur[t])
#define WSB_H2   (WSB_CUR + 65536)           // h2 staging [c][j][t_tile] fp32
#define WS_H2_F  ((WSB_H2) / 4)

__device__ __forceinline__ unsigned int fn_compose(unsigned int hi, unsigned int lo) {
  unsigned int r = 0;
  #pragma unroll
  for (int x = 0; x < 8; ++x) {
    unsigned int m = (lo >> (3 * x)) & 7u;
    r |= ((hi >> (3 * m)) & 7u) << (3 * x);
  }
  return r;
}

// ---------------- one merged prep launch ----------------
__global__ void __launch_bounds__(256) k_prepAll(
    const float* __restrict__ pa, const float* __restrict__ times,
    const float* __restrict__ gum, const int* __restrict__ edge,
    const float* __restrict__ W1, const float* __restrict__ b1,
    const float* __restrict__ W2, const float* __restrict__ W3,
    const float* __restrict__ W4,
    const float* __restrict__ D1, const float* __restrict__ d1,
    const float* __restrict__ D2, const float* __restrict__ d2,
    const float* __restrict__ D3, const float* __restrict__ d3,
    float* __restrict__ ws) {
  int b = blockIdx.x, tid = threadIdx.x;
  if (b < 128) {            // W2C: chunk-contiguous relayout of W2
    int e = b * 256 + tid;  // < 32768
    int jj = e & 31, k = (e >> 5) & 255, jc = e >> 13;
    ws[WS_W2C + e] = W2[(jc * 32 + jj) * 256 + k];
  } else if (b < 160) {     // W3T[j][i] = W3[i][j]
    int e = (b - 128) * 256 + tid;
    int i = e & 63, j = e >> 6;
    ws[WS_W3T + e] = W3[i * 128 + j];
  } else if (b < 672) {     // gumbels
    int e = (b - 160) * 256 + tid;
    float uu = gum[e];
    ws[WS_G + e] = -logf(-logf(uu + 1e-20f) + 1e-20f);
  } else if (b == 672) {    // setup: U, V, W1ZT, W4T, PEN
    {
      int k = tid;
      float acc = b1[k];
      #pragma unroll
      for (int i = 0; i < 8; ++i) acc = fmaf(pa[i], W1[k * 17 + i], acc);
      ws[WS_U + k] = acc;
      ws[WS_V + k] = W1[k * 17 + 8];
    }
    for (int e = tid; e < 2048; e += 256) {
      int cc = e >> 8, k = e & 255;
      ws[WS_W1ZT + e] = W1[k * 17 + 9 + cc];
    }
    for (int e = tid; e < 512; e += 256) {
      int k = e >> 3, z = e & 7;
      ws[WS_W4T + e] = W4[z * 64 + k];
    }
    if (tid < 64) ws[WS_A + tid] = ((tid >> 3) == (tid & 7)) ? 1.0f : 0.0f;
    __syncthreads();
    if (tid == 0) {
      for (int e = 0; e < 16; ++e) {
        int aa = edge[e], bb = edge[16 + e];
        ws[WS_A + aa * 8 + bb] = 1.0f;
        ws[WS_A + bb * 8 + aa] = 1.0f;
      }
    }
    __syncthreads();
    if (tid < 64) ws[WS_PEN + tid] = 1000.0f * (1.0f - ws[WS_A + tid]);
  } else {                  // diversity: blocks 673..736, thread = t
    int t = (b - 673) * 256 + tid;
    float last = times[T_STEPS - 1];
    float st = (last > 0.0f) ? times[t] / last : 0.0f;
    float h1d[128];
    #pragma unroll
    for (int k = 0; k < 128; ++k) {
      float a = d1[k];
      #pragma unroll
      for (int i2 = 0; i2 < 8; ++i2) a = fmaf(pa[i2], D1[k * 9 + i2], a);
      h1d[k] = fmaxf(fmaf(st, D1[k * 9 + 8], a), 0.0f);
    }
    float dva[8];
    #pragma unroll
    for (int z = 0; z < 8; ++z) dva[z] = d3[z];
    for (int i = 0; i < 64; ++i) {
      float a = d2[i];
      #pragma unroll
      for (int k = 0; k < 128; ++k) a = fmaf(D2[i * 128 + k], h1d[k], a);
      float h2 = fmaxf(a, 0.0f);
      #pragma unroll
      for (int z = 0; z < 8; ++z) dva[z] = fmaf(D3[z * 64 + i], h2, dva[z]);
    }
    #pragma unroll
    for (int z = 0; z < 8; ++z) ws[WS_DV + t * 8 + z] = tanhf(dva[z]);
  }
}

// ---------------- layer 1+2: thread = (t, c, jhalf); acc[32] only ----------------
__global__ void __launch_bounds__(256, 4) k_layer2(
    const float* __restrict__ times,
    const float* __restrict__ u_, const float* __restrict__ v_,
    const float* __restrict__ w1zt, const float* __restrict__ w2c,
    const float* __restrict__ b2,
    float* __restrict__ h2s, int t_base, int t_tile) {
  int W = blockIdx.x * 4 + (threadIdx.x >> 6);
  int lane = threadIdx.x & 63;
  int jh = __builtin_amdgcn_readfirstlane(W & 1);
  int c  = __builtin_amdgcn_readfirstlane((W >> 1) & 7);
  int tl = (W >> 4) * 64 + lane;
  int t  = t_base + tl;
  float last = times[T_STEPS - 1];
  float st = (last > 0.0f) ? times[t] / last : 0.0f;
  const float* w1c = w1zt + c * 256;
  for (int cc = 0; cc < 2; ++cc) {
    int jc = jh * 2 + cc;
    const float* wc = w2c + jc * 8192;
    const float* bb = b2 + jc * 32;
    float acc[32];
    #pragma unroll
    for (int jj = 0; jj < 32; ++jj) acc[jj] = bb[jj];
    #pragma unroll 2
    for (int k = 0; k < 256; ++k) {
      float h = fmaxf(fmaf(st, v_[k], u_[k]) + w1c[k], 0.0f);
      #pragma unroll
      for (int jj = 0; jj < 32; ++jj)
        acc[jj] = fmaf(wc[k * 32 + jj], h, acc[jj]);
    }
    float* dst = h2s + (size_t)(c * 128 + jc * 32) * t_tile + tl;
    #pragma unroll
    for (int jj = 0; jj < 32; ++jj)
      dst[(size_t)jj * t_tile] = fmaxf(acc[jj], 0.0f);  // store post-relu
  }
}

// ---------------- layer 3+4 + epilogue: thread = (t, c); acc3[64] only ----------------
__global__ void __launch_bounds__(256, 2) k_layer34(
    const float* __restrict__ w3t, const float* __restrict__ w4t,
    const float* __restrict__ b3, const float* __restrict__ b4,
    const float* __restrict__ dv, const float* __restrict__ gt,
    const float* __restrict__ pen, const float* __restrict__ tau,
    const float* __restrict__ h2s,
    float* __restrict__ cons_out, unsigned char* __restrict__ nxt_out,
    int t_base, int t_tile) {
  int W = blockIdx.x * 4 + (threadIdx.x >> 6);
  int lane = threadIdx.x & 63;
  int c = __builtin_amdgcn_readfirstlane(W & 7);
  int tl = (W >> 3) * 64 + lane;
  int t = t_base + tl;
  const float* hp = h2s + (size_t)c * 128 * t_tile + tl;

  float acc3[64];
  #pragma unroll
  for (int i = 0; i < 64; ++i) acc3[i] = b3[i];
  #pragma unroll 2
  for (int j = 0; j < 128; ++j) {
    float h2 = hp[(size_t)j * t_tile];
    #pragma unroll
    for (int i = 0; i < 64; ++i)
      acc3[i] = fmaf(w3t[j * 64 + i], h2, acc3[i]);
  }

  float a4[8];
  #pragma unroll
  for (int z = 0; z < 8; ++z) a4[z] = b4[z];
  #pragma unroll 8
  for (int i = 0; i < 64; ++i) {
    float h3 = fmaxf(acc3[i], 0.0f);
    #pragma unroll
    for (int z = 0; z < 8; ++z) a4[z] = fmaf(w4t[i * 8 + z], h3, a4[z]);
  }

  float4 dv0 = *(const float4*)(dv + (size_t)t * 8);
  float4 dv1 = *(const float4*)(dv + (size_t)t * 8 + 4);
  float4 g0  = *(const float4*)(gt + (size_t)t * 8);
  float4 g1  = *(const float4*)(gt + (size_t)t * 8 + 4);
  float dvv[8] = {dv0.x, dv0.y, dv0.z, dv0.w, dv1.x, dv1.y, dv1.z, dv1.w};
  float gv[8]  = {g0.x, g0.y, g0.z, g0.w, g1.x, g1.y, g1.z, g1.w};
  float sgn = (tau[0] > 0.0f) ? 1.0f : -1.0f;
  float cons[8];
  float best = 0.0f; int bz = 0;
  #pragma unroll
  for (int z = 0; z < 8; ++z) {
    float lg = fmaf(0.2f, dvv[z], a4[z]) - pen[c * 8 + z];
    cons[z] = lg;
    float yv = (lg + gv[z]) * sgn;
    if (z == 0) { best = yv; bz = 0; }
    else if (yv > best) { best = yv; bz = z; }
  }
  float* co = cons_out + ((size_t)t * 8 + c) * 8;
  *(float4*)co = make_float4(cons[0], cons[1], cons[2], cons[3]);
  *(float4*)(co + 4) = make_float4(cons[4], cons[5], cons[6], cons[7]);
  nxt_out[t * 8 + c] = (unsigned char)bz;
}

// ---------------- phase C: parallel prefix over transition functions ----------------
__global__ void __launch_bounds__(256) k_phaseC(float* __restrict__ ws, float* __restrict__ d_out) {
  int tid = threadIdx.x;
  const unsigned char* nxt8 = (const unsigned char*)ws + WSB_NXT8;
  unsigned int* cur_arr = (unsigned int*)((char*)ws + WSB_CUR);
  const unsigned int IDENT = 0x00FAC688u;
  unsigned int f[64];
  int t0 = tid * 64;
  unsigned int F = IDENT;
  #pragma unroll
  for (int i = 0; i < 64; ++i) {
    uint2 b = *(const uint2*)(nxt8 + (size_t)(t0 + i) * 8);
    unsigned int fn = 0;
    #pragma unroll
    for (int q = 0; q < 4; ++q) fn |= ((b.x >> (8 * q)) & 7u) << (3 * q);
    #pragma unroll
    for (int q = 0; q < 4; ++q) fn |= ((b.y >> (8 * q)) & 7u) << (3 * (q + 4));
    f[i] = fn;
    F = fn_compose(fn, F);
  }
  __shared__ unsigned int sc[256];
  sc[tid] = F;
  __syncthreads();
  #pragma unroll
  for (int d = 1; d < 256; d <<= 1) {
    unsigned int v = sc[tid];
    unsigned int p = (tid >= d) ? sc[tid - d] : 0u;
    unsigned int nv = (tid >= d) ? fn_compose(v, p) : v;
    __syncthreads();
    sc[tid] = nv;
    __syncthreads();
  }
  unsigned int E = (tid == 0) ? IDENT : sc[tid - 1];
  unsigned int state = E & 7u;
  #pragma unroll
  for (int i = 0; i < 64; ++i) {
    int tt = t0 + i;
    cur_arr[tt] = state;
    unsigned int nx = (f[i] >> (3 * state)) & 7u;
    d_out[131072 + tt] = (float)nx;
    state = nx;
  }
}

// ---------------- gather ----------------
__global__ void k_gather(const float* __restrict__ ws, float* __restrict__ d_out) {
  int idx = blockIdx.x * 256 + threadIdx.x;
  const unsigned int* cur_arr = (const unsigned int*)((const char*)ws + WSB_CUR);
  int t = idx >> 3, z = idx & 7;
  unsigned int cur = cur_arr[t];
  d_out[idx] = ws[WS_CONS + (t * 8 + (int)cur) * 8 + z];
}

extern "C" void kernel_launch(void* const* d_in, const int* in_sizes, int n_in,
                              void* d_out, int out_size, void* d_ws, size_t ws_size,
                              hipStream_t stream) {
  const float* pa    = (const float*)d_in[0];
  const float* times = (const float*)d_in[1];
  const float* gum   = (const float*)d_in[2];
  const int*   edge  = (const int*)d_in[3];
  const float* W1  = (const float*)d_in[4];
  const float* b1  = (const float*)d_in[5];
  const float* W2  = (const float*)d_in[6];
  const float* b2  = (const float*)d_in[7];
  const float* W3  = (const float*)d_in[8];
  const float* b3  = (const float*)d_in[9];
  const float* W4  = (const float*)d_in[10];
  const float* b4  = (const float*)d_in[11];
  const float* D1  = (const float*)d_in[12];
  const float* d1v = (const float*)d_in[13];
  const float* D2  = (const float*)d_in[14];
  const float* d2v = (const float*)d_in[15];
  const float* D3  = (const float*)d_in[16];
  const float* d3v = (const float*)d_in[17];
  const float* tau = (const float*)d_in[18];
  float* ws = (float*)d_ws;
  float* out = (float*)d_out;

  // adaptive t-tiling so h2 staging fits ws
  int t_tile = T_STEPS;
  {
    size_t avail = (ws_size > WSB_H2) ? (ws_size - WSB_H2) : 0;
    while ((size_t)8 * 128 * (size_t)t_tile * 4 > avail && t_tile > 512) t_tile >>= 1;
  }
  float* h2s = ws + WS_H2_F;

  k_prepAll<<<737, 256, 0, stream>>>(pa, times, gum, edge, W1, b1, W2, W3, W4,
                                     D1, d1v, D2, d2v, D3, d3v, ws);
  for (int tb = 0; tb < T_STEPS; tb += t_tile) {
    k_layer2<<<t_tile / 16, 256, 0, stream>>>(times, ws + WS_U, ws + WS_V,
                                              ws + WS_W1ZT, ws + WS_W2C, b2,
                                              h2s, tb, t_tile);
    k_layer34<<<t_tile / 32, 256, 0, stream>>>(ws + WS_W3T, ws + WS_W4T, b3, b4,
                                               ws + WS_DV, ws + WS_G, ws + WS_PEN,
                                               tau, h2s, ws + WS_CONS,
                                               (unsigned char*)ws + WSB_NXT8,
                                               tb, t_tile);
  }
  k_phaseC<<<1, 256, 0, stream>>>(ws, out);
  k_gather<<<512, 256, 0, stream>>>(ws, out);
}

// Round 5
// 192.312 us; speedup vs baseline: 1.9927x; 1.9107x over previous
//
#include <hip/hip_runtime.h>
#include <cstdint>

#define T_STEPS 16384

// ---- workspace float offsets ----
#define WS_U     0        // 256
#define WS_V     256      // 256
#define WS_W1ZT  512      // 2048 [c][k]
#define WS_PEN   2560     // 64
#define WS_A     2624     // 64
#define WS_W4T   2688     // 512 [i][z]
#define WS_UDC   3200     // 128
#define WS_VDC   3328     // 128
#define WS_D3T   3456     // 512 [k][z]
#define WS_W2C   3968     // 32768 [jc][k][jj]
#define WS_W3T   36736    // 8192 [j][i]
#define WS_D2T   44928    // 8192 [k][j]
#define WS_DV    53120    // 131072
#define WS_G     184192   // 131072
#define WS_CONS  315264   // 1048576
#define WS_END_F 1363840
#define WSB_NXT8 ((size_t)WS_END_F * 4)      // 131072 B (u8 nxt[t][c])
#define WSB_CUR  (WSB_NXT8 + 131072)         // 65536 B (u32 cur[t])
#define WSB_H2   (WSB_CUR + 65536)           // h2 [c][j][t_tile] fp32
#define WS_H2_F  ((WSB_H2) / 4)

__device__ __forceinline__ unsigned int fn_compose(unsigned int hi, unsigned int lo) {
  unsigned int r = 0;
  #pragma unroll
  for (int x = 0; x < 8; ++x) {
    unsigned int m = (lo >> (3 * x)) & 7u;
    r |= ((hi >> (3 * m)) & 7u) << (3 * x);
  }
  return r;
}

// ---------------- prep: relayouts + gumbel + setup (no big per-thread arrays) ----------------
__global__ void __launch_bounds__(256) k_prepAll(
    const float* __restrict__ pa, const float* __restrict__ gum,
    const int* __restrict__ edge,
    const float* __restrict__ W1, const float* __restrict__ b1,
    const float* __restrict__ W2, const float* __restrict__ W3,
    const float* __restrict__ W4,
    const float* __restrict__ D1, const float* __restrict__ d1,
    const float* __restrict__ D2, const float* __restrict__ D3,
    float* __restrict__ ws) {
  int b = blockIdx.x, tid = threadIdx.x;
  if (b < 128) {            // W2C[jc][k][jj] = W2[jc*32+jj][k]
    int e = b * 256 + tid;
    int jj = e & 31, k = (e >> 5) & 255, jc = e >> 13;
    ws[WS_W2C + e] = W2[(jc * 32 + jj) * 256 + k];
  } else if (b < 160) {     // W3T[j][i] = W3[i][j]
    int e = (b - 128) * 256 + tid;
    int i = e & 63, j = e >> 6;
    ws[WS_W3T + e] = W3[i * 128 + j];
  } else if (b < 192) {     // D2T[k][j] = D2[j][k]
    int e = (b - 160) * 256 + tid;
    int j = e >> 7, k = e & 127;
    ws[WS_D2T + k * 64 + j] = D2[e];
  } else if (b < 704) {     // gumbels
    int e = (b - 192) * 256 + tid;
    float uu = gum[e];
    ws[WS_G + e] = -logf(-logf(uu + 1e-20f) + 1e-20f);
  } else {                  // setup
    {
      int k = tid;
      float acc = b1[k];
      #pragma unroll
      for (int i = 0; i < 8; ++i) acc = fmaf(pa[i], W1[k * 17 + i], acc);
      ws[WS_U + k] = acc;
      ws[WS_V + k] = W1[k * 17 + 8];
    }
    if (tid < 128) {
      float acc = d1[tid];
      #pragma unroll
      for (int i = 0; i < 8; ++i) acc = fmaf(pa[i], D1[tid * 9 + i], acc);
      ws[WS_UDC + tid] = acc;
      ws[WS_VDC + tid] = D1[tid * 9 + 8];
    }
    for (int e = tid; e < 2048; e += 256) {
      int cc = e >> 8, k = e & 255;
      ws[WS_W1ZT + e] = W1[k * 17 + 9 + cc];
    }
    for (int e = tid; e < 512; e += 256) {
      int k = e >> 3, z = e & 7;
      ws[WS_W4T + e] = W4[z * 64 + k];
      ws[WS_D3T + e] = D3[z * 64 + k];
    }
    if (tid < 64) ws[WS_A + tid] = ((tid >> 3) == (tid & 7)) ? 1.0f : 0.0f;
    __syncthreads();
    if (tid == 0) {
      for (int e = 0; e < 16; ++e) {
        int aa = edge[e], bb = edge[16 + e];
        ws[WS_A + aa * 8 + bb] = 1.0f;
        ws[WS_A + bb * 8 + aa] = 1.0f;
      }
    }
    __syncthreads();
    if (tid < 64) ws[WS_PEN + tid] = 1000.0f * (1.0f - ws[WS_A + tid]);
  }
}

// ---------------- diversity (R1 LDS design): dv[t][8] ----------------
__global__ void __launch_bounds__(256) k_diversity(
    const float* __restrict__ times, const float* __restrict__ d2,
    const float* __restrict__ d3, float* __restrict__ ws) {
  __shared__ float h1dT[128][64];
  __shared__ float h2dT[64][64];
  int tid = threadIdx.x;
  int s = tid & 63, w = tid >> 6;
  int t = blockIdx.x * 64 + s;
  float last = times[T_STEPS - 1];
  float st = (last > 0.0f) ? times[t] / last : 0.0f;
  int j0 = __builtin_amdgcn_readfirstlane(w * 32);
  #pragma unroll
  for (int jj = 0; jj < 32; ++jj) {
    int j = j0 + jj;
    h1dT[j][s] = fmaxf(fmaf(st, ws[WS_VDC + j], ws[WS_UDC + j]), 0.0f);
  }
  __syncthreads();
  j0 = __builtin_amdgcn_readfirstlane(w * 16);
  float acc[16];
  #pragma unroll
  for (int jj = 0; jj < 16; ++jj) acc[jj] = d2[j0 + jj];
  #pragma unroll 4
  for (int k = 0; k < 128; ++k) {
    float h = h1dT[k][s];
    #pragma unroll
    for (int jj = 0; jj < 16; ++jj)
      acc[jj] = fmaf(ws[WS_D2T + k * 64 + j0 + jj], h, acc[jj]);
  }
  #pragma unroll
  for (int jj = 0; jj < 16; ++jj) h2dT[j0 + jj][s] = fmaxf(acc[jj], 0.0f);
  __syncthreads();
  if (tid < 64) {
    float a8[8];
    #pragma unroll
    for (int z = 0; z < 8; ++z) a8[z] = d3[z];
    #pragma unroll 4
    for (int k = 0; k < 64; ++k) {
      float h = h2dT[k][s];
      #pragma unroll
      for (int z = 0; z < 8; ++z) a8[z] = fmaf(ws[WS_D3T + k * 8 + z], h, a8[z]);
    }
    #pragma unroll
    for (int z = 0; z < 8; ++z) ws[WS_DV + t * 8 + z] = tanhf(a8[z]);
  }
}

// ---------------- layer 1+2: thread=(t,c,jhalf); acc[32] (known-good from R3) ----------------
__global__ void __launch_bounds__(256, 4) k_layer2(
    const float* __restrict__ times,
    const float* __restrict__ u_, const float* __restrict__ v_,
    const float* __restrict__ w1zt, const float* __restrict__ w2c,
    const float* __restrict__ b2,
    float* __restrict__ h2s, int t_base, int t_tile) {
  int W = blockIdx.x * 4 + (threadIdx.x >> 6);
  int lane = threadIdx.x & 63;
  int jh = __builtin_amdgcn_readfirstlane(W & 1);
  int c  = __builtin_amdgcn_readfirstlane((W >> 1) & 7);
  int tl = (W >> 4) * 64 + lane;
  int t  = t_base + tl;
  float last = times[T_STEPS - 1];
  float st = (last > 0.0f) ? times[t] / last : 0.0f;
  const float* w1c = w1zt + c * 256;
  for (int cc = 0; cc < 2; ++cc) {
    int jc = jh * 2 + cc;
    const float* wc = w2c + jc * 8192;
    const float* bb = b2 + jc * 32;
    float acc[32];
    #pragma unroll
    for (int jj = 0; jj < 32; ++jj) acc[jj] = bb[jj];
    #pragma unroll 2
    for (int k = 0; k < 256; ++k) {
      float h = fmaxf(fmaf(st, v_[k], u_[k]) + w1c[k], 0.0f);
      #pragma unroll
      for (int jj = 0; jj < 32; ++jj)
        acc[jj] = fmaf(wc[k * 32 + jj], h, acc[jj]);
    }
    float* dst = h2s + (size_t)(c * 128 + jc * 32) * t_tile + tl;
    #pragma unroll
    for (int jj = 0; jj < 32; ++jj)
      dst[(size_t)jj * t_tile] = fmaxf(acc[jj], 0.0f);
  }
}

// ---------------- fused layer3+4+epilogue: wave=(cb,ih), acc[32] + LDS combine ----------------
__global__ void __launch_bounds__(512, 4) k_layer34v2(
    const float* __restrict__ w3t, const float* __restrict__ w4t,
    const float* __restrict__ b3, const float* __restrict__ b4,
    const float* __restrict__ dv, const float* __restrict__ gt,
    const float* __restrict__ pen, const float* __restrict__ tau,
    const float* __restrict__ h2s,
    float* __restrict__ cons_out, unsigned char* __restrict__ nxt_out,
    int t_base, int t_tile) {
  __shared__ float part[4][8][64];  // 8KB: partial a4 from ih=1 waves
  int tid = threadIdx.x;
  int lane = tid & 63;
  int wv = __builtin_amdgcn_readfirstlane(tid >> 6);  // 0..7
  int cb = wv >> 1, ih = wv & 1;
  int tgrp = blockIdx.x >> 1, chalf = blockIdx.x & 1;
  int c = chalf * 4 + cb;
  int tl = tgrp * 64 + lane;
  int t = t_base + tl;
  const float* hp = h2s + (size_t)(c * 128) * t_tile + tl;
  const float* w3 = w3t + ih * 32;

  float acc[32];  // h3 outputs [ih*32, ih*32+32)
  #pragma unroll
  for (int i = 0; i < 32; ++i) acc[i] = b3[ih * 32 + i];
  #pragma unroll 4
  for (int j = 0; j < 128; ++j) {
    float h2 = hp[(size_t)j * t_tile];
    #pragma unroll
    for (int i = 0; i < 32; ++i)
      acc[i] = fmaf(w3[j * 64 + i], h2, acc[i]);
  }

  // partial layer 4 over own 32 h3's
  float p[8];
  #pragma unroll
  for (int z = 0; z < 8; ++z) p[z] = (ih == 0) ? b4[z] : 0.0f;
  #pragma unroll 4
  for (int i = 0; i < 32; ++i) {
    float h3 = fmaxf(acc[i], 0.0f);
    #pragma unroll
    for (int z = 0; z < 8; ++z)
      p[z] = fmaf(w4t[(ih * 32 + i) * 8 + z], h3, p[z]);
  }
  if (ih == 1) {
    #pragma unroll
    for (int z = 0; z < 8; ++z) part[cb][z][lane] = p[z];
  }
  __syncthreads();
  if (ih == 0) {
    float a4[8];
    #pragma unroll
    for (int z = 0; z < 8; ++z) a4[z] = p[z] + part[cb][z][lane];
    float4 dv0 = *(const float4*)(dv + (size_t)t * 8);
    float4 dv1 = *(const float4*)(dv + (size_t)t * 8 + 4);
    float4 g0  = *(const float4*)(gt + (size_t)t * 8);
    float4 g1  = *(const float4*)(gt + (size_t)t * 8 + 4);
    float dvv[8] = {dv0.x, dv0.y, dv0.z, dv0.w, dv1.x, dv1.y, dv1.z, dv1.w};
    float gv[8]  = {g0.x, g0.y, g0.z, g0.w, g1.x, g1.y, g1.z, g1.w};
    float sgn = (tau[0] > 0.0f) ? 1.0f : -1.0f;
    float cons[8];
    float best = 0.0f; int bz = 0;
    #pragma unroll
    for (int z = 0; z < 8; ++z) {
      float lg = fmaf(0.2f, dvv[z], a4[z]) - pen[c * 8 + z];
      cons[z] = lg;
      float yv = (lg + gv[z]) * sgn;
      if (z == 0) { best = yv; bz = 0; }
      else if (yv > best) { best = yv; bz = z; }
    }
    float* co = cons_out + ((size_t)t * 8 + c) * 8;
    *(float4*)co = make_float4(cons[0], cons[1], cons[2], cons[3]);
    *(float4*)(co + 4) = make_float4(cons[4], cons[5], cons[6], cons[7]);
    nxt_out[t * 8 + c] = (unsigned char)bz;
  }
}

// ---------------- phase C: parallel prefix over transition functions ----------------
__global__ void __launch_bounds__(256) k_phaseC(float* __restrict__ ws, float* __restrict__ d_out) {
  int tid = threadIdx.x;
  const unsigned char* nxt8 = (const unsigned char*)ws + WSB_NXT8;
  unsigned int* cur_arr = (unsigned int*)((char*)ws + WSB_CUR);
  const unsigned int IDENT = 0x00FAC688u;
  unsigned int f[64];
  int t0 = tid * 64;
  unsigned int F = IDENT;
  #pragma unroll
  for (int i = 0; i < 64; ++i) {
    uint2 b = *(const uint2*)(nxt8 + (size_t)(t0 + i) * 8);
    unsigned int fn = 0;
    #pragma unroll
    for (int q = 0; q < 4; ++q) fn |= ((b.x >> (8 * q)) & 7u) << (3 * q);
    #pragma unroll
    for (int q = 0; q < 4; ++q) fn |= ((b.y >> (8 * q)) & 7u) << (3 * (q + 4));
    f[i] = fn;
    F = fn_compose(fn, F);
  }
  __shared__ unsigned int sc[256];
  sc[tid] = F;
  __syncthreads();
  #pragma unroll
  for (int d = 1; d < 256; d <<= 1) {
    unsigned int v = sc[tid];
    unsigned int p = (tid >= d) ? sc[tid - d] : 0u;
    unsigned int nv = (tid >= d) ? fn_compose(v, p) : v;
    __syncthreads();
    sc[tid] = nv;
    __syncthreads();
  }
  unsigned int E = (tid == 0) ? IDENT : sc[tid - 1];
  unsigned int state = E & 7u;
  #pragma unroll
  for (int i = 0; i < 64; ++i) {
    int tt = t0 + i;
    cur_arr[tt] = state;
    unsigned int nx = (f[i] >> (3 * state)) & 7u;
    d_out[131072 + tt] = (float)nx;
    state = nx;
  }
}

// ---------------- gather ----------------
__global__ void k_gather(const float* __restrict__ ws, float* __restrict__ d_out) {
  int idx = blockIdx.x * 256 + threadIdx.x;
  const unsigned int* cur_arr = (const unsigned int*)((const char*)ws + WSB_CUR);
  int t = idx >> 3, z = idx & 7;
  unsigned int cur = cur_arr[t];
  d_out[idx] = ws[WS_CONS + (t * 8 + (int)cur) * 8 + z];
}

extern "C" void kernel_launch(void* const* d_in, const int* in_sizes, int n_in,
                              void* d_out, int out_size, void* d_ws, size_t ws_size,
                              hipStream_t stream) {
  const float* pa    = (const float*)d_in[0];
  const float* times = (const float*)d_in[1];
  const float* gum   = (const float*)d_in[2];
  const int*   edge  = (const int*)d_in[3];
  const float* W1  = (const float*)d_in[4];
  const float* b1  = (const float*)d_in[5];
  const float* W2  = (const float*)d_in[6];
  const float* b2  = (const float*)d_in[7];
  const float* W3  = (const float*)d_in[8];
  const float* b3  = (const float*)d_in[9];
  const float* W4  = (const float*)d_in[10];
  const float* b4  = (const float*)d_in[11];
  const float* D1  = (const float*)d_in[12];
  const float* d1v = (const float*)d_in[13];
  const float* D2  = (const float*)d_in[14];
  const float* d2v = (const float*)d_in[15];
  const float* D3  = (const float*)d_in[16];
  const float* d3v = (const float*)d_in[17];
  const float* tau = (const float*)d_in[18];
  float* ws = (float*)d_ws;
  float* out = (float*)d_out;

  int t_tile = T_STEPS;
  {
    size_t avail = (ws_size > WSB_H2) ? (ws_size - WSB_H2) : 0;
    while ((size_t)8 * 128 * (size_t)t_tile * 4 > avail && t_tile > 1024) t_tile >>= 1;
  }
  float* h2s = ws + WS_H2_F;

  k_prepAll<<<705, 256, 0, stream>>>(pa, gum, edge, W1, b1, W2, W3, W4,
                                     D1, d1v, D2, D3, ws);
  k_diversity<<<256, 256, 0, stream>>>(times, d2v, d3v, ws);
  for (int tb = 0; tb < T_STEPS; tb += t_tile) {
    k_layer2<<<t_tile / 16, 256, 0, stream>>>(times, ws + WS_U, ws + WS_V,
                                              ws + WS_W1ZT, ws + WS_W2C, b2,
                                              h2s, tb, t_tile);
    k_layer34v2<<<(t_tile / 64) * 2, 512, 0, stream>>>(
        ws + WS_W3T, ws + WS_W4T, b3, b4, ws + WS_DV, ws + WS_G, ws + WS_PEN,
        tau, h2s, ws + WS_CONS, (unsigned char*)ws + WSB_NXT8, tb, t_tile);
  }
  k_phaseC<<<1, 256, 0, stream>>>(ws, out);
  k_gather<<<512, 256, 0, stream>>>(ws, out);
}

// Round 6
// 187.536 us; speedup vs baseline: 2.0435x; 1.0255x over previous
//
#include <hip/hip_runtime.h>
#include <cstdint>

#define T_STEPS 16384

// ---- workspace float offsets ----
#define WS_U     0        // 256
#define WS_V     256      // 256
#define WS_W1ZT  512      // 2048 [c][k]
#define WS_PEN   2560     // 64
#define WS_A     2624     // 64
#define WS_W4T   2688     // 512 [i][z]
#define WS_UDC   3200     // 128
#define WS_VDC   3328     // 128
#define WS_D3T   3456     // 512 [k][z]
#define WS_W2C   3968     // 32768 [jc][k][jj]
#define WS_W3T   36736    // 8192 [j][i]
#define WS_D2T   44928    // 8192 [k][j]
#define WS_DV    53120    // 131072
#define WS_G     184192   // 131072
#define WS_CONS  315264   // 1048576
#define WS_END_F 1363840
#define WSB_NXT8 ((size_t)WS_END_F * 4)      // 131072 B (u8 nxt[t][c])
#define WSB_CUR  (WSB_NXT8 + 131072)         // 65536 B (u32 cur[t])
#define WSB_H2   (WSB_CUR + 65536)           // h2 [c][j][t_tile] fp32
#define WS_H2_F  ((WSB_H2) / 4)

__device__ __forceinline__ unsigned int fn_compose(unsigned int hi, unsigned int lo) {
  unsigned int r = 0;
  #pragma unroll
  for (int x = 0; x < 8; ++x) {
    unsigned int m = (lo >> (3 * x)) & 7u;
    r |= ((hi >> (3 * m)) & 7u) << (3 * x);
  }
  return r;
}

// ---------------- prep: relayouts + gumbel + setup ----------------
__global__ void __launch_bounds__(256) k_prepAll(
    const float* __restrict__ pa, const float* __restrict__ gum,
    const int* __restrict__ edge,
    const float* __restrict__ W1, const float* __restrict__ b1,
    const float* __restrict__ W2, const float* __restrict__ W3,
    const float* __restrict__ W4,
    const float* __restrict__ D1, const float* __restrict__ d1,
    const float* __restrict__ D2, const float* __restrict__ D3,
    float* __restrict__ ws) {
  int b = blockIdx.x, tid = threadIdx.x;
  if (b < 128) {            // W2C[jc][k][jj] = W2[jc*32+jj][k]
    int e = b * 256 + tid;
    int jj = e & 31, k = (e >> 5) & 255, jc = e >> 13;
    ws[WS_W2C + e] = W2[(jc * 32 + jj) * 256 + k];
  } else if (b < 160) {     // W3T[j][i] = W3[i][j]
    int e = (b - 128) * 256 + tid;
    int i = e & 63, j = e >> 6;
    ws[WS_W3T + e] = W3[i * 128 + j];
  } else if (b < 192) {     // D2T[k][j] = D2[j][k]
    int e = (b - 160) * 256 + tid;
    int j = e >> 7, k = e & 127;
    ws[WS_D2T + k * 64 + j] = D2[e];
  } else if (b < 704) {     // gumbels
    int e = (b - 192) * 256 + tid;
    float uu = gum[e];
    ws[WS_G + e] = -logf(-logf(uu + 1e-20f) + 1e-20f);
  } else {                  // setup
    {
      int k = tid;
      float acc = b1[k];
      #pragma unroll
      for (int i = 0; i < 8; ++i) acc = fmaf(pa[i], W1[k * 17 + i], acc);
      ws[WS_U + k] = acc;
      ws[WS_V + k] = W1[k * 17 + 8];
    }
    if (tid < 128) {
      float acc = d1[tid];
      #pragma unroll
      for (int i = 0; i < 8; ++i) acc = fmaf(pa[i], D1[tid * 9 + i], acc);
      ws[WS_UDC + tid] = acc;
      ws[WS_VDC + tid] = D1[tid * 9 + 8];
    }
    for (int e = tid; e < 2048; e += 256) {
      int cc = e >> 8, k = e & 255;
      ws[WS_W1ZT + e] = W1[k * 17 + 9 + cc];
    }
    for (int e = tid; e < 512; e += 256) {
      int k = e >> 3, z = e & 7;
      ws[WS_W4T + e] = W4[z * 64 + k];
      ws[WS_D3T + e] = D3[z * 64 + k];
    }
    if (tid < 64) ws[WS_A + tid] = ((tid >> 3) == (tid & 7)) ? 1.0f : 0.0f;
    __syncthreads();
    if (tid == 0) {
      for (int e = 0; e < 16; ++e) {
        int aa = edge[e], bb = edge[16 + e];
        ws[WS_A + aa * 8 + bb] = 1.0f;
        ws[WS_A + bb * 8 + aa] = 1.0f;
      }
    }
    __syncthreads();
    if (tid < 64) ws[WS_PEN + tid] = 1000.0f * (1.0f - ws[WS_A + tid]);
  }
}

// ---------------- diversity (LDS design): dv[t][8] ----------------
__global__ void __launch_bounds__(256) k_diversity(
    const float* __restrict__ times, const float* __restrict__ d2,
    const float* __restrict__ d3, float* __restrict__ ws) {
  __shared__ float h1dT[128][64];
  __shared__ float h2dT[64][64];
  int tid = threadIdx.x;
  int s = tid & 63, w = tid >> 6;
  int t = blockIdx.x * 64 + s;
  float last = times[T_STEPS - 1];
  float st = (last > 0.0f) ? times[t] / last : 0.0f;
  int j0 = __builtin_amdgcn_readfirstlane(w * 32);
  #pragma unroll
  for (int jj = 0; jj < 32; ++jj) {
    int j = j0 + jj;
    h1dT[j][s] = fmaxf(fmaf(st, ws[WS_VDC + j], ws[WS_UDC + j]), 0.0f);
  }
  __syncthreads();
  j0 = __builtin_amdgcn_readfirstlane(w * 16);
  float acc[16];
  #pragma unroll
  for (int jj = 0; jj < 16; ++jj) acc[jj] = d2[j0 + jj];
  #pragma unroll 4
  for (int k = 0; k < 128; ++k) {
    float h = h1dT[k][s];
    #pragma unroll
    for (int jj = 0; jj < 16; ++jj)
      acc[jj] = fmaf(ws[WS_D2T + k * 64 + j0 + jj], h, acc[jj]);
  }
  #pragma unroll
  for (int jj = 0; jj < 16; ++jj) h2dT[j0 + jj][s] = fmaxf(acc[jj], 0.0f);
  __syncthreads();
  if (tid < 64) {
    float a8[8];
    #pragma unroll
    for (int z = 0; z < 8; ++z) a8[z] = d3[z];
    #pragma unroll 4
    for (int k = 0; k < 64; ++k) {
      float h = h2dT[k][s];
      #pragma unroll
      for (int z = 0; z < 8; ++z) a8[z] = fmaf(ws[WS_D3T + k * 8 + z], h, a8[z]);
    }
    #pragma unroll
    for (int z = 0; z < 8; ++z) ws[WS_DV + t * 8 + z] = tanhf(a8[z]);
  }
}

// ---------------- layer 1+2: thread=(t,c,jc); acc[32]; full occupancy ----------------
__global__ void __launch_bounds__(256, 8) k_layer2(
    const float* __restrict__ times,
    const float* __restrict__ u_, const float* __restrict__ v_,
    const float* __restrict__ w1zt, const float* __restrict__ w2c,
    const float* __restrict__ b2,
    float* __restrict__ h2s, int t_base, int t_tile) {
  int W = blockIdx.x * 4 + (threadIdx.x >> 6);
  int lane = threadIdx.x & 63;
  int jc = __builtin_amdgcn_readfirstlane(W & 3);
  int c  = __builtin_amdgcn_readfirstlane((W >> 2) & 7);
  int tl = (W >> 5) * 64 + lane;
  int t  = t_base + tl;
  float last = times[T_STEPS - 1];
  float st = (last > 0.0f) ? times[t] / last : 0.0f;
  const float* w1c = w1zt + c * 256;
  const float* wc = w2c + jc * 8192;
  const float* bb = b2 + jc * 32;
  float acc[32];
  #pragma unroll
  for (int jj = 0; jj < 32; ++jj) acc[jj] = bb[jj];
  #pragma unroll 2
  for (int k = 0; k < 256; ++k) {
    float h = fmaxf(fmaf(st, v_[k], u_[k]) + w1c[k], 0.0f);
    #pragma unroll
    for (int jj = 0; jj < 32; ++jj)
      acc[jj] = fmaf(wc[k * 32 + jj], h, acc[jj]);
  }
  float* dst = h2s + (size_t)(c * 128 + jc * 32) * t_tile + tl;
  #pragma unroll
  for (int jj = 0; jj < 32; ++jj)
    dst[(size_t)jj * t_tile] = fmaxf(acc[jj], 0.0f);
}

// ---------------- fused layer3+4+epilogue: wave=(cb,ih), acc[32] + LDS combine ----------------
__global__ void __launch_bounds__(512, 4) k_layer34v2(
    const float* __restrict__ w3t, const float* __restrict__ w4t,
    const float* __restrict__ b3, const float* __restrict__ b4,
    const float* __restrict__ dv, const float* __restrict__ gt,
    const float* __restrict__ pen, const float* __restrict__ tau,
    const float* __restrict__ h2s,
    float* __restrict__ cons_out, unsigned char* __restrict__ nxt_out,
    int t_base, int t_tile) {
  __shared__ float part[4][8][64];
  int tid = threadIdx.x;
  int lane = tid & 63;
  int wv = __builtin_amdgcn_readfirstlane(tid >> 6);
  int cb = wv >> 1, ih = wv & 1;
  int tgrp = blockIdx.x >> 1, chalf = blockIdx.x & 1;
  int c = chalf * 4 + cb;
  int tl = tgrp * 64 + lane;
  int t = t_base + tl;
  const float* hp = h2s + (size_t)(c * 128) * t_tile + tl;
  const float* w3 = w3t + ih * 32;

  float acc[32];
  #pragma unroll
  for (int i = 0; i < 32; ++i) acc[i] = b3[ih * 32 + i];
  #pragma unroll 4
  for (int j = 0; j < 128; ++j) {
    float h2 = hp[(size_t)j * t_tile];
    #pragma unroll
    for (int i = 0; i < 32; ++i)
      acc[i] = fmaf(w3[j * 64 + i], h2, acc[i]);
  }

  float p[8];
  #pragma unroll
  for (int z = 0; z < 8; ++z) p[z] = (ih == 0) ? b4[z] : 0.0f;
  #pragma unroll 4
  for (int i = 0; i < 32; ++i) {
    float h3 = fmaxf(acc[i], 0.0f);
    #pragma unroll
    for (int z = 0; z < 8; ++z)
      p[z] = fmaf(w4t[(ih * 32 + i) * 8 + z], h3, p[z]);
  }
  if (ih == 1) {
    #pragma unroll
    for (int z = 0; z < 8; ++z) part[cb][z][lane] = p[z];
  }
  __syncthreads();
  if (ih == 0) {
    float a4[8];
    #pragma unroll
    for (int z = 0; z < 8; ++z) a4[z] = p[z] + part[cb][z][lane];
    float4 dv0 = *(const float4*)(dv + (size_t)t * 8);
    float4 dv1 = *(const float4*)(dv + (size_t)t * 8 + 4);
    float4 g0  = *(const float4*)(gt + (size_t)t * 8);
    float4 g1  = *(const float4*)(gt + (size_t)t * 8 + 4);
    float dvv[8] = {dv0.x, dv0.y, dv0.z, dv0.w, dv1.x, dv1.y, dv1.z, dv1.w};
    float gv[8]  = {g0.x, g0.y, g0.z, g0.w, g1.x, g1.y, g1.z, g1.w};
    float sgn = (tau[0] > 0.0f) ? 1.0f : -1.0f;
    float cons[8];
    float best = 0.0f; int bz = 0;
    #pragma unroll
    for (int z = 0; z < 8; ++z) {
      float lg = fmaf(0.2f, dvv[z], a4[z]) - pen[c * 8 + z];
      cons[z] = lg;
      float yv = (lg + gv[z]) * sgn;
      if (z == 0) { best = yv; bz = 0; }
      else if (yv > best) { best = yv; bz = z; }
    }
    float* co = cons_out + ((size_t)t * 8 + c) * 8;
    *(float4*)co = make_float4(cons[0], cons[1], cons[2], cons[3]);
    *(float4*)(co + 4) = make_float4(cons[4], cons[5], cons[6], cons[7]);
    nxt_out[t * 8 + c] = (unsigned char)bz;
  }
}

// ---------------- phase C: parallel prefix over transition functions ----------------
__global__ void __launch_bounds__(256) k_phaseC(float* __restrict__ ws, float* __restrict__ d_out) {
  int tid = threadIdx.x;
  const unsigned char* nxt8 = (const unsigned char*)ws + WSB_NXT8;
  unsigned int* cur_arr = (unsigned int*)((char*)ws + WSB_CUR);
  const unsigned int IDENT = 0x00FAC688u;
  unsigned int f[64];
  int t0 = tid * 64;
  unsigned int F = IDENT;
  #pragma unroll
  for (int i = 0; i < 64; ++i) {
    uint2 b = *(const uint2*)(nxt8 + (size_t)(t0 + i) * 8);
    unsigned int fn = 0;
    #pragma unroll
    for (int q = 0; q < 4; ++q) fn |= ((b.x >> (8 * q)) & 7u) << (3 * q);
    #pragma unroll
    for (int q = 0; q < 4; ++q) fn |= ((b.y >> (8 * q)) & 7u) << (3 * (q + 4));
    f[i] = fn;
    F = fn_compose(fn, F);
  }
  __shared__ unsigned int sc[256];
  sc[tid] = F;
  __syncthreads();
  #pragma unroll
  for (int d = 1; d < 256; d <<= 1) {
    unsigned int v = sc[tid];
    unsigned int p = (tid >= d) ? sc[tid - d] : 0u;
    unsigned int nv = (tid >= d) ? fn_compose(v, p) : v;
    __syncthreads();
    sc[tid] = nv;
    __syncthreads();
  }
  unsigned int E = (tid == 0) ? IDENT : sc[tid - 1];
  unsigned int state = E & 7u;
  #pragma unroll
  for (int i = 0; i < 64; ++i) {
    int tt = t0 + i;
    cur_arr[tt] = state;
    unsigned int nx = (f[i] >> (3 * state)) & 7u;
    d_out[131072 + tt] = (float)nx;
    state = nx;
  }
}

// ---------------- gather ----------------
__global__ void k_gather(const float* __restrict__ ws, float* __restrict__ d_out) {
  int idx = blockIdx.x * 256 + threadIdx.x;
  const unsigned int* cur_arr = (const unsigned int*)((const char*)ws + WSB_CUR);
  int t = idx >> 3, z = idx & 7;
  unsigned int cur = cur_arr[t];
  d_out[idx] = ws[WS_CONS + (t * 8 + (int)cur) * 8 + z];
}

extern "C" void kernel_launch(void* const* d_in, const int* in_sizes, int n_in,
                              void* d_out, int out_size, void* d_ws, size_t ws_size,
                              hipStream_t stream) {
  const float* pa    = (const float*)d_in[0];
  const float* times = (const float*)d_in[1];
  const float* gum   = (const float*)d_in[2];
  const int*   edge  = (const int*)d_in[3];
  const float* W1  = (const float*)d_in[4];
  const float* b1  = (const float*)d_in[5];
  const float* W2  = (const float*)d_in[6];
  const float* b2  = (const float*)d_in[7];
  const float* W3  = (const float*)d_in[8];
  const float* b3  = (const float*)d_in[9];
  const float* W4  = (const float*)d_in[10];
  const float* b4  = (const float*)d_in[11];
  const float* D1  = (const float*)d_in[12];
  const float* d1v = (const float*)d_in[13];
  const float* D2  = (const float*)d_in[14];
  const float* d2v = (const float*)d_in[15];
  const float* D3  = (const float*)d_in[16];
  const float* d3v = (const float*)d_in[17];
  const float* tau = (const float*)d_in[18];
  float* ws = (float*)d_ws;
  float* out = (float*)d_out;

  int t_tile = T_STEPS;
  {
    size_t avail = (ws_size > WSB_H2) ? (ws_size - WSB_H2) : 0;
    while ((size_t)8 * 128 * (size_t)t_tile * 4 > avail && t_tile > 1024) t_tile >>= 1;
  }
  float* h2s = ws + WS_H2_F;

  k_prepAll<<<705, 256, 0, stream>>>(pa, gum, edge, W1, b1, W2, W3, W4,
                                     D1, d1v, D2, D3, ws);
  k_diversity<<<256, 256, 0, stream>>>(times, d2v, d3v, ws);
  for (int tb = 0; tb < T_STEPS; tb += t_tile) {
    k_layer2<<<t_tile / 8, 256, 0, stream>>>(times, ws + WS_U, ws + WS_V,
                                             ws + WS_W1ZT, ws + WS_W2C, b2,
                                             h2s, tb, t_tile);
    k_layer34v2<<<(t_tile / 64) * 2, 512, 0, stream>>>(
        ws + WS_W3T, ws + WS_W4T, b3, b4, ws + WS_DV, ws + WS_G, ws + WS_PEN,
        tau, h2s, ws + WS_CONS, (unsigned char*)ws + WSB_NXT8, tb, t_tile);
  }
  k_phaseC<<<1, 256, 0, stream>>>(ws, out);
  k_gather<<<512, 256, 0, stream>>>(ws, out);
}

// Round 7
// 150.922 us; speedup vs baseline: 2.5392x; 1.2426x over previous
//
#include <hip/hip_runtime.h>
#include <cstdint>

#define T_STEPS 16384

// ---- workspace float offsets ----
#define WS_U     0        // 256
#define WS_V     256      // 256
#define WS_W1ZT  512      // 2048 [c][k]
#define WS_PEN   2560     // 64
#define WS_A     2624     // 64
#define WS_W4T   2688     // 512 [i][z]
#define WS_UDC   3200     // 128
#define WS_VDC   3328     // 128
#define WS_D3T   3456     // 512 [k][z]
#define WS_W2T   3968     // 32768 [k][j] 256x128
#define WS_W3T   36736    // 8192 [j][i]
#define WS_D2T   44928    // 8192 [k][j]
#define WS_DV    53120    // 131072
#define WS_G     184192   // 131072
#define WS_CONS  315264   // 1048576
#define WS_ABT   1363840  // 524288: ABt[c][tile64][j][2] (A includes b2)
#define WS_END_F 1888128
#define WSB_NXT8 ((size_t)WS_END_F * 4)      // 131072 B (u8 nxt[t][c])
#define WSB_CUR  (WSB_NXT8 + 131072)         // 65536 B (u32 cur[t])
#define WSB_CRX  (WSB_CUR + 65536)           // int CRX[8][256][12]: count + 8 k's

__device__ __forceinline__ unsigned int fn_compose(unsigned int hi, unsigned int lo) {
  unsigned int r = 0;
  #pragma unroll
  for (int x = 0; x < 8; ++x) {
    unsigned int m = (lo >> (3 * x)) & 7u;
    r |= ((hi >> (3 * m)) & 7u) << (3 * x);
  }
  return r;
}

// ---------------- prep: relayouts + gumbel + setup ----------------
__global__ void __launch_bounds__(256) k_prepAll(
    const float* __restrict__ pa, const float* __restrict__ gum,
    const int* __restrict__ edge,
    const float* __restrict__ W1, const float* __restrict__ b1,
    const float* __restrict__ W2, const float* __restrict__ W3,
    const float* __restrict__ W4,
    const float* __restrict__ D1, const float* __restrict__ d1,
    const float* __restrict__ D2, const float* __restrict__ D3,
    float* __restrict__ ws) {
  int b = blockIdx.x, tid = threadIdx.x;
  if (b < 128) {            // W2T[k][j] = W2[j][k]
    int e = b * 256 + tid;
    int k = e >> 7, j = e & 127;
    ws[WS_W2T + e] = W2[j * 256 + k];
  } else if (b < 160) {     // W3T[j][i] = W3[i][j]
    int e = (b - 128) * 256 + tid;
    int i = e & 63, j = e >> 6;
    ws[WS_W3T + e] = W3[i * 128 + j];
  } else if (b < 192) {     // D2T[k][j] = D2[j][k]
    int e = (b - 160) * 256 + tid;
    int j = e >> 7, k = e & 127;
    ws[WS_D2T + k * 64 + j] = D2[e];
  } else if (b < 704) {     // gumbels
    int e = (b - 192) * 256 + tid;
    float uu = gum[e];
    ws[WS_G + e] = -logf(-logf(uu + 1e-20f) + 1e-20f);
  } else {                  // setup
    {
      int k = tid;
      float acc = b1[k];
      #pragma unroll
      for (int i = 0; i < 8; ++i) acc = fmaf(pa[i], W1[k * 17 + i], acc);
      ws[WS_U + k] = acc;
      ws[WS_V + k] = W1[k * 17 + 8];
    }
    if (tid < 128) {
      float acc = d1[tid];
      #pragma unroll
      for (int i = 0; i < 8; ++i) acc = fmaf(pa[i], D1[tid * 9 + i], acc);
      ws[WS_UDC + tid] = acc;
      ws[WS_VDC + tid] = D1[tid * 9 + 8];
    }
    for (int e = tid; e < 2048; e += 256) {
      int cc = e >> 8, k = e & 255;
      ws[WS_W1ZT + e] = W1[k * 17 + 9 + cc];
    }
    for (int e = tid; e < 512; e += 256) {
      int k = e >> 3, z = e & 7;
      ws[WS_W4T + e] = W4[z * 64 + k];
      ws[WS_D3T + e] = D3[z * 64 + k];
    }
    if (tid < 64) ws[WS_A + tid] = ((tid >> 3) == (tid & 7)) ? 1.0f : 0.0f;
    __syncthreads();
    if (tid == 0) {
      for (int e = 0; e < 16; ++e) {
        int aa = edge[e], bb = edge[16 + e];
        ws[WS_A + aa * 8 + bb] = 1.0f;
        ws[WS_A + bb * 8 + aa] = 1.0f;
      }
    }
    __syncthreads();
    if (tid < 64) ws[WS_PEN + tid] = 1000.0f * (1.0f - ws[WS_A + tid]);
  }
}

// ---------------- diversity (LDS design): dv[t][8] ----------------
__global__ void __launch_bounds__(256) k_diversity(
    const float* __restrict__ times, const float* __restrict__ d2,
    const float* __restrict__ d3, float* __restrict__ ws) {
  __shared__ float h1dT[128][64];
  __shared__ float h2dT[64][64];
  int tid = threadIdx.x;
  int s = tid & 63, w = tid >> 6;
  int t = blockIdx.x * 64 + s;
  float last = times[T_STEPS - 1];
  float st = (last > 0.0f) ? times[t] / last : 0.0f;
  int j0 = __builtin_amdgcn_readfirstlane(w * 32);
  #pragma unroll
  for (int jj = 0; jj < 32; ++jj) {
    int j = j0 + jj;
    h1dT[j][s] = fmaxf(fmaf(st, ws[WS_VDC + j], ws[WS_UDC + j]), 0.0f);
  }
  __syncthreads();
  j0 = __builtin_amdgcn_readfirstlane(w * 16);
  float acc[16];
  #pragma unroll
  for (int jj = 0; jj < 16; ++jj) acc[jj] = d2[j0 + jj];
  #pragma unroll 4
  for (int k = 0; k < 128; ++k) {
    float h = h1dT[k][s];
    #pragma unroll
    for (int jj = 0; jj < 16; ++jj)
      acc[jj] = fmaf(ws[WS_D2T + k * 64 + j0 + jj], h, acc[jj]);
  }
  #pragma unroll
  for (int jj = 0; jj < 16; ++jj) h2dT[j0 + jj][s] = fmaxf(acc[jj], 0.0f);
  __syncthreads();
  if (tid < 64) {
    float a8[8];
    #pragma unroll
    for (int z = 0; z < 8; ++z) a8[z] = d3[z];
    #pragma unroll 4
    for (int k = 0; k < 64; ++k) {
      float h = h2dT[k][s];
      #pragma unroll
      for (int z = 0; z < 8; ++z) a8[z] = fmaf(ws[WS_D3T + k * 8 + z], h, a8[z]);
    }
    #pragma unroll
    for (int z = 0; z < 8; ++z) ws[WS_DV + t * 8 + z] = tanhf(a8[z]);
  }
}

// ---------------- AB precompute: per (c, 64-t tile) affine h2 coefficients ----------------
__global__ void __launch_bounds__(128) k_ab(
    const float* __restrict__ times,
    const float* __restrict__ u_, const float* __restrict__ v_,
    const float* __restrict__ w1zt, const float* __restrict__ w2t,
    const float* __restrict__ b2,
    float* __restrict__ abt, int* __restrict__ crx) {
  int blk = blockIdx.x;             // c*256 + tile
  int c = blk >> 8, tile = blk & 255;
  int j = threadIdx.x;              // 128
  float last = times[T_STEPS - 1];
  float stL = (last > 0.0f) ? times[tile * 64] / last : 0.0f;
  float stR = (last > 0.0f) ? times[tile * 64 + 63] / last : 0.0f;
  const float* w1c = w1zt + c * 256;
  __shared__ int s_cnt;
  __shared__ int s_list[8];
  if (j == 0) s_cnt = 0;
  if (j < 8) s_list[j] = 0;
  __syncthreads();
  float A = b2[j], B = 0.0f;
  for (int k = 0; k < 256; ++k) {
    float uk = u_[k] + w1c[k];
    float vk = v_[k];
    float valL = fmaf(stL, vk, uk);
    float valR = fmaf(stR, vk, uk);
    float mn = fminf(valL, valR);
    float mx = fmaxf(valL, valR);
    if (mn > 0.0f) {                // active across whole tile (affine => bound by endpoints)
      float w = w2t[k * 128 + j];
      A = fmaf(uk, w, A);
      B = fmaf(vk, w, B);
    } else if (mx > 0.0f) {         // relu crossing inside tile
      if (j == 0) {
        int idx = s_cnt;
        s_cnt = idx + 1;
        if (idx < 8) s_list[idx] = k;
      }
    }                               // else inactive: contributes 0
  }
  __syncthreads();
  abt[(size_t)blk * 256 + j * 2] = A;
  abt[(size_t)blk * 256 + j * 2 + 1] = B;
  if (j == 0) crx[blk * 12] = s_cnt;
  if (j < 8) crx[blk * 12 + 1 + j] = s_list[j];
}

// ---------------- fused MLP: h2 from (A,B) -> layer3 -> layer4 -> epilogue ----------------
__global__ void __launch_bounds__(512, 4) k_mlp(
    const float* __restrict__ times,
    const float* __restrict__ u_, const float* __restrict__ v_,
    const float* __restrict__ w1zt, const float* __restrict__ w2t,
    const float* __restrict__ abt, const int* __restrict__ crx,
    const float* __restrict__ w3t, const float* __restrict__ w4t,
    const float* __restrict__ b2, const float* __restrict__ b3,
    const float* __restrict__ b4,
    const float* __restrict__ dv, const float* __restrict__ gt,
    const float* __restrict__ pen, const float* __restrict__ tau,
    float* __restrict__ cons_out, unsigned char* __restrict__ nxt_out) {
  __shared__ float part[4][8][64];
  int tid = threadIdx.x;
  int lane = tid & 63;
  int wv = __builtin_amdgcn_readfirstlane(tid >> 6);
  int cb = wv >> 1, ih = wv & 1;
  int tgrp = blockIdx.x >> 1, chalf = blockIdx.x & 1;
  int c = chalf * 4 + cb;
  int t = tgrp * 64 + lane;
  float last = times[T_STEPS - 1];
  float st = (last > 0.0f) ? times[t] / last : 0.0f;
  const float* w1c = w1zt + c * 256;
  int abase = (c * 256 + tgrp) * 256;
  int cbase = (c * 256 + tgrp) * 12;
  int cnt = crx[cbase];

  float acc[32];
  #pragma unroll
  for (int i = 0; i < 32; ++i) acc[i] = b3[ih * 32 + i];
  const float* w3 = w3t + ih * 32;

  if (cnt == 0) {
    #pragma unroll 4
    for (int j = 0; j < 128; ++j) {
      float A = abt[abase + j * 2];
      float B = abt[abase + j * 2 + 1];
      float h2 = fmaxf(fmaf(st, B, A), 0.0f);
      #pragma unroll
      for (int i = 0; i < 32; ++i)
        acc[i] = fmaf(w3[j * 64 + i], h2, acc[i]);
    }
  } else if (cnt <= 8) {
    int kk[8];
    #pragma unroll
    for (int i = 0; i < 8; ++i) kk[i] = (i < cnt) ? crx[cbase + 1 + i] : 0;
    float hx[8];
    #pragma unroll
    for (int i = 0; i < 8; ++i)
      hx[i] = (i < cnt) ? fmaxf(fmaf(st, v_[kk[i]], u_[kk[i]] + w1c[kk[i]]), 0.0f) : 0.0f;
    #pragma unroll 2
    for (int j = 0; j < 128; ++j) {
      float A = abt[abase + j * 2];
      float B = abt[abase + j * 2 + 1];
      float h2p = fmaf(st, B, A);
      #pragma unroll
      for (int i = 0; i < 8; ++i)
        h2p = fmaf(hx[i], w2t[kk[i] * 128 + j], h2p);
      float h2 = fmaxf(h2p, 0.0f);
      #pragma unroll
      for (int i = 0; i < 32; ++i)
        acc[i] = fmaf(w3[j * 64 + i], h2, acc[i]);
    }
  } else {
    // exact brute-force fallback (vanishingly rare)
    for (int j = 0; j < 128; ++j) {
      float h2p = b2[j];
      for (int k = 0; k < 256; ++k) {
        float h1 = fmaxf(fmaf(st, v_[k], u_[k] + w1c[k]), 0.0f);
        h2p = fmaf(w2t[k * 128 + j], h1, h2p);
      }
      float h2 = fmaxf(h2p, 0.0f);
      #pragma unroll
      for (int i = 0; i < 32; ++i)
        acc[i] = fmaf(w3[j * 64 + i], h2, acc[i]);
    }
  }

  // layer 4 partials
  float p[8];
  #pragma unroll
  for (int z = 0; z < 8; ++z) p[z] = (ih == 0) ? b4[z] : 0.0f;
  #pragma unroll 4
  for (int i = 0; i < 32; ++i) {
    float h3 = fmaxf(acc[i], 0.0f);
    #pragma unroll
    for (int z = 0; z < 8; ++z)
      p[z] = fmaf(w4t[(ih * 32 + i) * 8 + z], h3, p[z]);
  }
  if (ih == 1) {
    #pragma unroll
    for (int z = 0; z < 8; ++z) part[cb][z][lane] = p[z];
  }
  __syncthreads();
  if (ih == 0) {
    float a4[8];
    #pragma unroll
    for (int z = 0; z < 8; ++z) a4[z] = p[z] + part[cb][z][lane];
    float4 dv0 = *(const float4*)(dv + (size_t)t * 8);
    float4 dv1 = *(const float4*)(dv + (size_t)t * 8 + 4);
    float4 g0  = *(const float4*)(gt + (size_t)t * 8);
    float4 g1  = *(const float4*)(gt + (size_t)t * 8 + 4);
    float dvv[8] = {dv0.x, dv0.y, dv0.z, dv0.w, dv1.x, dv1.y, dv1.z, dv1.w};
    float gv[8]  = {g0.x, g0.y, g0.z, g0.w, g1.x, g1.y, g1.z, g1.w};
    float sgn = (tau[0] > 0.0f) ? 1.0f : -1.0f;
    float cons[8];
    float best = 0.0f; int bz = 0;
    #pragma unroll
    for (int z = 0; z < 8; ++z) {
      float lg = fmaf(0.2f, dvv[z], a4[z]) - pen[c * 8 + z];
      cons[z] = lg;
      float yv = (lg + gv[z]) * sgn;
      if (z == 0) { best = yv; bz = 0; }
      else if (yv > best) { best = yv; bz = z; }
    }
    float* co = cons_out + ((size_t)t * 8 + c) * 8;
    *(float4*)co = make_float4(cons[0], cons[1], cons[2], cons[3]);
    *(float4*)(co + 4) = make_float4(cons[4], cons[5], cons[6], cons[7]);
    nxt_out[t * 8 + c] = (unsigned char)bz;
  }
}

// ---------------- phase C: parallel prefix over transition functions ----------------
__global__ void __launch_bounds__(256) k_phaseC(float* __restrict__ ws, float* __restrict__ d_out) {
  int tid = threadIdx.x;
  const unsigned char* nxt8 = (const unsigned char*)ws + WSB_NXT8;
  unsigned int* cur_arr = (unsigned int*)((char*)ws + WSB_CUR);
  const unsigned int IDENT = 0x00FAC688u;
  unsigned int f[64];
  int t0 = tid * 64;
  unsigned int F = IDENT;
  #pragma unroll
  for (int i = 0; i < 64; ++i) {
    uint2 b = *(const uint2*)(nxt8 + (size_t)(t0 + i) * 8);
    unsigned int fn = 0;
    #pragma unroll
    for (int q = 0; q < 4; ++q) fn |= ((b.x >> (8 * q)) & 7u) << (3 * q);
    #pragma unroll
    for (int q = 0; q < 4; ++q) fn |= ((b.y >> (8 * q)) & 7u) << (3 * (q + 4));
    f[i] = fn;
    F = fn_compose(fn, F);
  }
  __shared__ unsigned int sc[256];
  sc[tid] = F;
  __syncthreads();
  #pragma unroll
  for (int d = 1; d < 256; d <<= 1) {
    unsigned int v = sc[tid];
    unsigned int p = (tid >= d) ? sc[tid - d] : 0u;
    unsigned int nv = (tid >= d) ? fn_compose(v, p) : v;
    __syncthreads();
    sc[tid] = nv;
    __syncthreads();
  }
  unsigned int E = (tid == 0) ? IDENT : sc[tid - 1];
  unsigned int state = E & 7u;
  #pragma unroll
  for (int i = 0; i < 64; ++i) {
    int tt = t0 + i;
    cur_arr[tt] = state;
    unsigned int nx = (f[i] >> (3 * state)) & 7u;
    d_out[131072 + tt] = (float)nx;
    state = nx;
  }
}

// ---------------- gather ----------------
__global__ void k_gather(const float* __restrict__ ws, float* __restrict__ d_out) {
  int idx = blockIdx.x * 256 + threadIdx.x;
  const unsigned int* cur_arr = (const unsigned int*)((const char*)ws + WSB_CUR);
  int t = idx >> 3, z = idx & 7;
  unsigned int cur = cur_arr[t];
  d_out[idx] = ws[WS_CONS + (t * 8 + (int)cur) * 8 + z];
}

extern "C" void kernel_launch(void* const* d_in, const int* in_sizes, int n_in,
                              void* d_out, int out_size, void* d_ws, size_t ws_size,
                              hipStream_t stream) {
  const float* pa    = (const float*)d_in[0];
  const float* times = (const float*)d_in[1];
  const float* gum   = (const float*)d_in[2];
  const int*   edge  = (const int*)d_in[3];
  const float* W1  = (const float*)d_in[4];
  const float* b1  = (const float*)d_in[5];
  const float* W2  = (const float*)d_in[6];
  const float* b2  = (const float*)d_in[7];
  const float* W3  = (const float*)d_in[8];
  const float* b3  = (const float*)d_in[9];
  const float* W4  = (const float*)d_in[10];
  const float* b4  = (const float*)d_in[11];
  const float* D1  = (const float*)d_in[12];
  const float* d1v = (const float*)d_in[13];
  const float* D2  = (const float*)d_in[14];
  const float* d2v = (const float*)d_in[15];
  const float* D3  = (const float*)d_in[16];
  const float* d3v = (const float*)d_in[17];
  const float* tau = (const float*)d_in[18];
  float* ws = (float*)d_ws;
  float* out = (float*)d_out;
  int* crx = (int*)((char*)d_ws + WSB_CRX);

  k_prepAll<<<705, 256, 0, stream>>>(pa, gum, edge, W1, b1, W2, W3, W4,
                                     D1, d1v, D2, D3, ws);
  k_diversity<<<256, 256, 0, stream>>>(times, d2v, d3v, ws);
  k_ab<<<2048, 128, 0, stream>>>(times, ws + WS_U, ws + WS_V, ws + WS_W1ZT,
                                 ws + WS_W2T, b2, ws + WS_ABT, crx);
  k_mlp<<<512, 512, 0, stream>>>(times, ws + WS_U, ws + WS_V, ws + WS_W1ZT,
                                 ws + WS_W2T, ws + WS_ABT, crx,
                                 ws + WS_W3T, ws + WS_W4T, b2, b3, b4,
                                 ws + WS_DV, ws + WS_G, ws + WS_PEN, tau,
                                 ws + WS_CONS, (unsigned char*)ws + WSB_NXT8);
  k_phaseC<<<1, 256, 0, stream>>>(ws, out);
  k_gather<<<512, 256, 0, stream>>>(ws, out);
}

// Round 8
// 109.985 us; speedup vs baseline: 3.4844x; 1.3722x over previous
//
#include <hip/hip_runtime.h>
#include <cstdint>

#define T_STEPS 16384

// ---- workspace float offsets ----
#define WS_U     0        // 256
#define WS_V     256      // 256
#define WS_W1ZT  512      // 2048 [c][k]
#define WS_PEN   2560     // 64
#define WS_A     2624     // 64
#define WS_W4T   2688     // 512 [i][z]
#define WS_UDC   3200     // 128
#define WS_VDC   3328     // 128
#define WS_D3T   3456     // 512 [k][z]
#define WS_W2T   3968     // 32768 [k][j] 256x128
#define WS_W3T   36736    // 8192 [j][i]
#define WS_D2T   44928    // 8192 [k][j]
#define WS_DV    53120    // 131072
#define WS_G     184192   // 131072
#define WS_CONS  315264   // 1048576
#define WS_ABT   1363840  // 524288: ABt[c][tile64][j][2] (A includes b2)
#define WS_END_F 1888128
#define WSB_NXT8 ((size_t)WS_END_F * 4)      // 131072 B (u8 nxt[t][c])
#define WSB_CUR  (WSB_NXT8 + 131072)         // 65536 B (u32 cur[t])
#define WSB_CRX  (WSB_CUR + 65536)           // int CRX[8][256][12]: count + 8 k's

__device__ __forceinline__ unsigned int fn_compose(unsigned int hi, unsigned int lo) {
  unsigned int r = 0;
  #pragma unroll
  for (int x = 0; x < 8; ++x) {
    unsigned int m = (lo >> (3 * x)) & 7u;
    r |= ((hi >> (3 * m)) & 7u) << (3 * x);
  }
  return r;
}

// ---------------- prep: relayouts + gumbel + setup ----------------
__global__ void __launch_bounds__(256) k_prepAll(
    const float* __restrict__ pa, const float* __restrict__ gum,
    const int* __restrict__ edge,
    const float* __restrict__ W1, const float* __restrict__ b1,
    const float* __restrict__ W2, const float* __restrict__ W3,
    const float* __restrict__ W4,
    const float* __restrict__ D1, const float* __restrict__ d1,
    const float* __restrict__ D2, const float* __restrict__ D3,
    float* __restrict__ ws) {
  int b = blockIdx.x, tid = threadIdx.x;
  if (b < 128) {            // W2T[k][j] = W2[j][k]
    int e = b * 256 + tid;
    int k = e >> 7, j = e & 127;
    ws[WS_W2T + e] = W2[j * 256 + k];
  } else if (b < 160) {     // W3T[j][i] = W3[i][j]
    int e = (b - 128) * 256 + tid;
    int i = e & 63, j = e >> 6;
    ws[WS_W3T + e] = W3[i * 128 + j];
  } else if (b < 192) {     // D2T[k][j] = D2[j][k]
    int e = (b - 160) * 256 + tid;
    int j = e >> 7, k = e & 127;
    ws[WS_D2T + k * 64 + j] = D2[e];
  } else if (b < 704) {     // gumbels
    int e = (b - 192) * 256 + tid;
    float uu = gum[e];
    ws[WS_G + e] = -logf(-logf(uu + 1e-20f) + 1e-20f);
  } else {                  // setup
    {
      int k = tid;
      float acc = b1[k];
      #pragma unroll
      for (int i = 0; i < 8; ++i) acc = fmaf(pa[i], W1[k * 17 + i], acc);
      ws[WS_U + k] = acc;
      ws[WS_V + k] = W1[k * 17 + 8];
    }
    if (tid < 128) {
      float acc = d1[tid];
      #pragma unroll
      for (int i = 0; i < 8; ++i) acc = fmaf(pa[i], D1[tid * 9 + i], acc);
      ws[WS_UDC + tid] = acc;
      ws[WS_VDC + tid] = D1[tid * 9 + 8];
    }
    for (int e = tid; e < 2048; e += 256) {
      int cc = e >> 8, k = e & 255;
      ws[WS_W1ZT + e] = W1[k * 17 + 9 + cc];
    }
    for (int e = tid; e < 512; e += 256) {
      int k = e >> 3, z = e & 7;
      ws[WS_W4T + e] = W4[z * 64 + k];
      ws[WS_D3T + e] = D3[z * 64 + k];
    }
    if (tid < 64) ws[WS_A + tid] = ((tid >> 3) == (tid & 7)) ? 1.0f : 0.0f;
    __syncthreads();
    if (tid == 0) {
      for (int e = 0; e < 16; ++e) {
        int aa = edge[e], bb = edge[16 + e];
        ws[WS_A + aa * 8 + bb] = 1.0f;
        ws[WS_A + bb * 8 + aa] = 1.0f;
      }
    }
    __syncthreads();
    if (tid < 64) ws[WS_PEN + tid] = 1000.0f * (1.0f - ws[WS_A + tid]);
  }
}

// ---------------- diversity (LDS design): dv[t][8] ----------------
__global__ void __launch_bounds__(256) k_diversity(
    const float* __restrict__ times, const float* __restrict__ d2,
    const float* __restrict__ d3, float* __restrict__ ws) {
  __shared__ float h1dT[128][64];
  __shared__ float h2dT[64][64];
  int tid = threadIdx.x;
  int s = tid & 63, w = tid >> 6;
  int t = blockIdx.x * 64 + s;
  float last = times[T_STEPS - 1];
  float st = (last > 0.0f) ? times[t] / last : 0.0f;
  int j0 = __builtin_amdgcn_readfirstlane(w * 32);
  #pragma unroll
  for (int jj = 0; jj < 32; ++jj) {
    int j = j0 + jj;
    h1dT[j][s] = fmaxf(fmaf(st, ws[WS_VDC + j], ws[WS_UDC + j]), 0.0f);
  }
  __syncthreads();
  j0 = __builtin_amdgcn_readfirstlane(w * 16);
  float acc[16];
  #pragma unroll
  for (int jj = 0; jj < 16; ++jj) acc[jj] = d2[j0 + jj];
  #pragma unroll 4
  for (int k = 0; k < 128; ++k) {
    float h = h1dT[k][s];
    #pragma unroll
    for (int jj = 0; jj < 16; ++jj)
      acc[jj] = fmaf(ws[WS_D2T + k * 64 + j0 + jj], h, acc[jj]);
  }
  #pragma unroll
  for (int jj = 0; jj < 16; ++jj) h2dT[j0 + jj][s] = fmaxf(acc[jj], 0.0f);
  __syncthreads();
  if (tid < 64) {
    float a8[8];
    #pragma unroll
    for (int z = 0; z < 8; ++z) a8[z] = d3[z];
    #pragma unroll 4
    for (int k = 0; k < 64; ++k) {
      float h = h2dT[k][s];
      #pragma unroll
      for (int z = 0; z < 8; ++z) a8[z] = fmaf(ws[WS_D3T + k * 8 + z], h, a8[z]);
    }
    #pragma unroll
    for (int z = 0; z < 8; ++z) ws[WS_DV + t * 8 + z] = tanhf(a8[z]);
  }
}

// ---------------- AB precompute v2: parallel classify + unconditional masked matvec ----------------
__global__ void __launch_bounds__(256) k_ab2(
    const float* __restrict__ times,
    const float* __restrict__ u_, const float* __restrict__ v_,
    const float* __restrict__ w1zt, const float* __restrict__ w2t,
    const float* __restrict__ b2,
    float* __restrict__ abt, int* __restrict__ crx) {
  __shared__ float s_au[256], s_av[256];
  __shared__ float s_pa[128], s_pb[128];
  __shared__ unsigned long long s_bal[4];
  int blk = blockIdx.x;             // c*256 + tile
  int c = blk >> 8, tile = blk & 255;
  int tid = threadIdx.x;            // 256
  float last = times[T_STEPS - 1];
  float stL = (last > 0.0f) ? times[tile * 64] / last : 0.0f;
  float stR = (last > 0.0f) ? times[tile * 64 + 63] / last : 0.0f;

  // phase 1: classify k = tid (identical predicate to R6)
  {
    float uk = u_[tid] + w1zt[c * 256 + tid];
    float vk = v_[tid];
    float valL = fmaf(stL, vk, uk);
    float valR = fmaf(stR, vk, uk);
    float mn = fminf(valL, valR);
    float mx = fmaxf(valL, valR);
    bool act = (mn > 0.0f);
    bool cross = (!act) && (mx > 0.0f);
    s_au[tid] = act ? uk : 0.0f;
    s_av[tid] = act ? vk : 0.0f;
    unsigned long long bal = __ballot(cross);
    if ((tid & 63) == 0) s_bal[tid >> 6] = bal;
  }
  __syncthreads();

  // crossing list, deterministic k-order (wave-major bit scan)
  if (tid == 0) {
    int cnt = 0;
    int list8[8];
    #pragma unroll
    for (int i = 0; i < 8; ++i) list8[i] = 0;
    #pragma unroll
    for (int w = 0; w < 4; ++w) {
      unsigned long long m = s_bal[w];
      while (m) {
        int bit = __ffsll(m) - 1;
        if (cnt < 8) list8[cnt] = w * 64 + bit;
        ++cnt;
        m &= (m - 1);
      }
    }
    crx[blk * 12] = cnt;
    #pragma unroll
    for (int i = 0; i < 8; ++i) crx[blk * 12 + 1 + i] = list8[i];
  }

  // phase 2: unconditional masked matvec; thread = (j, k-half)
  int j = tid & 127, half = tid >> 7;
  float A = 0.0f, B = 0.0f;
  const float* wrow = w2t + half * 128 * 128 + j;
  int kb = half * 128;
  #pragma unroll 4
  for (int kk = 0; kk < 128; ++kk) {
    float w = wrow[kk * 128];
    A = fmaf(s_au[kb + kk], w, A);
    B = fmaf(s_av[kb + kk], w, B);
  }
  if (half == 1) { s_pa[j] = A; s_pb[j] = B; }
  __syncthreads();
  if (half == 0) {
    abt[(size_t)blk * 256 + j * 2]     = A + s_pa[j] + b2[j];
    abt[(size_t)blk * 256 + j * 2 + 1] = B + s_pb[j];
  }
}

// ---------------- fused MLP: h2 from (A,B) -> layer3 -> layer4 -> epilogue ----------------
__global__ void __launch_bounds__(512, 4) k_mlp(
    const float* __restrict__ times,
    const float* __restrict__ u_, const float* __restrict__ v_,
    const float* __restrict__ w1zt, const float* __restrict__ w2t,
    const float* __restrict__ abt, const int* __restrict__ crx,
    const float* __restrict__ w3t, const float* __restrict__ w4t,
    const float* __restrict__ b2, const float* __restrict__ b3,
    const float* __restrict__ b4,
    const float* __restrict__ dv, const float* __restrict__ gt,
    const float* __restrict__ pen, const float* __restrict__ tau,
    float* __restrict__ cons_out, unsigned char* __restrict__ nxt_out) {
  __shared__ float part[4][8][64];
  int tid = threadIdx.x;
  int lane = tid & 63;
  int wv = __builtin_amdgcn_readfirstlane(tid >> 6);
  int cb = wv >> 1, ih = wv & 1;
  int tgrp = blockIdx.x >> 1, chalf = blockIdx.x & 1;
  int c = chalf * 4 + cb;
  int t = tgrp * 64 + lane;
  float last = times[T_STEPS - 1];
  float st = (last > 0.0f) ? times[t] / last : 0.0f;
  const float* w1c = w1zt + c * 256;
  int abase = (c * 256 + tgrp) * 256;
  int cbase = (c * 256 + tgrp) * 12;
  int cnt = crx[cbase];

  float acc[32];
  #pragma unroll
  for (int i = 0; i < 32; ++i) acc[i] = b3[ih * 32 + i];
  const float* w3 = w3t + ih * 32;

  if (cnt == 0) {
    #pragma unroll 4
    for (int j = 0; j < 128; ++j) {
      float A = abt[abase + j * 2];
      float B = abt[abase + j * 2 + 1];
      float h2 = fmaxf(fmaf(st, B, A), 0.0f);
      #pragma unroll
      for (int i = 0; i < 32; ++i)
        acc[i] = fmaf(w3[j * 64 + i], h2, acc[i]);
    }
  } else if (cnt <= 8) {
    int kk[8];
    #pragma unroll
    for (int i = 0; i < 8; ++i) kk[i] = (i < cnt) ? crx[cbase + 1 + i] : 0;
    float hx[8];
    #pragma unroll
    for (int i = 0; i < 8; ++i)
      hx[i] = (i < cnt) ? fmaxf(fmaf(st, v_[kk[i]], u_[kk[i]] + w1c[kk[i]]), 0.0f) : 0.0f;
    #pragma unroll 2
    for (int j = 0; j < 128; ++j) {
      float A = abt[abase + j * 2];
      float B = abt[abase + j * 2 + 1];
      float h2p = fmaf(st, B, A);
      #pragma unroll
      for (int i = 0; i < 8; ++i)
        h2p = fmaf(hx[i], w2t[kk[i] * 128 + j], h2p);
      float h2 = fmaxf(h2p, 0.0f);
      #pragma unroll
      for (int i = 0; i < 32; ++i)
        acc[i] = fmaf(w3[j * 64 + i], h2, acc[i]);
    }
  } else {
    // exact brute-force fallback (vanishingly rare)
    for (int j = 0; j < 128; ++j) {
      float h2p = b2[j];
      for (int k = 0; k < 256; ++k) {
        float h1 = fmaxf(fmaf(st, v_[k], u_[k] + w1c[k]), 0.0f);
        h2p = fmaf(w2t[k * 128 + j], h1, h2p);
      }
      float h2 = fmaxf(h2p, 0.0f);
      #pragma unroll
      for (int i = 0; i < 32; ++i)
        acc[i] = fmaf(w3[j * 64 + i], h2, acc[i]);
    }
  }

  // layer 4 partials
  float p[8];
  #pragma unroll
  for (int z = 0; z < 8; ++z) p[z] = (ih == 0) ? b4[z] : 0.0f;
  #pragma unroll 4
  for (int i = 0; i < 32; ++i) {
    float h3 = fmaxf(acc[i], 0.0f);
    #pragma unroll
    for (int z = 0; z < 8; ++z)
      p[z] = fmaf(w4t[(ih * 32 + i) * 8 + z], h3, p[z]);
  }
  if (ih == 1) {
    #pragma unroll
    for (int z = 0; z < 8; ++z) part[cb][z][lane] = p[z];
  }
  __syncthreads();
  if (ih == 0) {
    float a4[8];
    #pragma unroll
    for (int z = 0; z < 8; ++z) a4[z] = p[z] + part[cb][z][lane];
    float4 dv0 = *(const float4*)(dv + (size_t)t * 8);
    float4 dv1 = *(const float4*)(dv + (size_t)t * 8 + 4);
    float4 g0  = *(const float4*)(gt + (size_t)t * 8);
    float4 g1  = *(const float4*)(gt + (size_t)t * 8 + 4);
    float dvv[8] = {dv0.x, dv0.y, dv0.z, dv0.w, dv1.x, dv1.y, dv1.z, dv1.w};
    float gv[8]  = {g0.x, g0.y, g0.z, g0.w, g1.x, g1.y, g1.z, g1.w};
    float sgn = (tau[0] > 0.0f) ? 1.0f : -1.0f;
    float cons[8];
    float best = 0.0f; int bz = 0;
    #pragma unroll
    for (int z = 0; z < 8; ++z) {
      float lg = fmaf(0.2f, dvv[z], a4[z]) - pen[c * 8 + z];
      cons[z] = lg;
      float yv = (lg + gv[z]) * sgn;
      if (z == 0) { best = yv; bz = 0; }
      else if (yv > best) { best = yv; bz = z; }
    }
    float* co = cons_out + ((size_t)t * 8 + c) * 8;
    *(float4*)co = make_float4(cons[0], cons[1], cons[2], cons[3]);
    *(float4*)(co + 4) = make_float4(cons[4], cons[5], cons[6], cons[7]);
    nxt_out[t * 8 + c] = (unsigned char)bz;
  }
}

// ---------------- phase C: parallel prefix, 1024 threads x 16 steps ----------------
__global__ void __launch_bounds__(1024) k_phaseC(float* __restrict__ ws, float* __restrict__ d_out) {
  int tid = threadIdx.x;
  const unsigned char* nxt8 = (const unsigned char*)ws + WSB_NXT8;
  unsigned int* cur_arr = (unsigned int*)((char*)ws + WSB_CUR);
  const unsigned int IDENT = 0x00FAC688u;
  unsigned int f[16];
  int t0 = tid * 16;
  unsigned int F = IDENT;
  #pragma unroll
  for (int i = 0; i < 16; ++i) {
    uint2 b = *(const uint2*)(nxt8 + (size_t)(t0 + i) * 8);
    unsigned int fn = 0;
    #pragma unroll
    for (int q = 0; q < 4; ++q) fn |= ((b.x >> (8 * q)) & 7u) << (3 * q);
    #pragma unroll
    for (int q = 0; q < 4; ++q) fn |= ((b.y >> (8 * q)) & 7u) << (3 * (q + 4));
    f[i] = fn;
    F = fn_compose(fn, F);
  }
  __shared__ unsigned int sc[1024];
  sc[tid] = F;
  __syncthreads();
  #pragma unroll
  for (int d = 1; d < 1024; d <<= 1) {
    unsigned int v = sc[tid];
    unsigned int p = (tid >= d) ? sc[tid - d] : 0u;
    unsigned int nv = (tid >= d) ? fn_compose(v, p) : v;
    __syncthreads();
    sc[tid] = nv;
    __syncthreads();
  }
  unsigned int E = (tid == 0) ? IDENT : sc[tid - 1];
  unsigned int state = E & 7u;
  #pragma unroll
  for (int i = 0; i < 16; ++i) {
    int tt = t0 + i;
    cur_arr[tt] = state;
    unsigned int nx = (f[i] >> (3 * state)) & 7u;
    d_out[131072 + tt] = (float)nx;
    state = nx;
  }
}

// ---------------- gather ----------------
__global__ void k_gather(const float* __restrict__ ws, float* __restrict__ d_out) {
  int idx = blockIdx.x * 256 + threadIdx.x;
  const unsigned int* cur_arr = (const unsigned int*)((const char*)ws + WSB_CUR);
  int t = idx >> 3, z = idx & 7;
  unsigned int cur = cur_arr[t];
  d_out[idx] = ws[WS_CONS + (t * 8 + (int)cur) * 8 + z];
}

extern "C" void kernel_launch(void* const* d_in, const int* in_sizes, int n_in,
                              void* d_out, int out_size, void* d_ws, size_t ws_size,
                              hipStream_t stream) {
  const float* pa    = (const float*)d_in[0];
  const float* times = (const float*)d_in[1];
  const float* gum   = (const float*)d_in[2];
  const int*   edge  = (const int*)d_in[3];
  const float* W1  = (const float*)d_in[4];
  const float* b1  = (const float*)d_in[5];
  const float* W2  = (const float*)d_in[6];
  const float* b2  = (const float*)d_in[7];
  const float* W3  = (const float*)d_in[8];
  const float* b3  = (const float*)d_in[9];
  const float* W4  = (const float*)d_in[10];
  const float* b4  = (const float*)d_in[11];
  const float* D1  = (const float*)d_in[12];
  const float* d1v = (const float*)d_in[13];
  const float* D2  = (const float*)d_in[14];
  const float* d2v = (const float*)d_in[15];
  const float* D3  = (const float*)d_in[16];
  const float* d3v = (const float*)d_in[17];
  const float* tau = (const float*)d_in[18];
  float* ws = (float*)d_ws;
  float* out = (float*)d_out;
  int* crx = (int*)((char*)d_ws + WSB_CRX);

  k_prepAll<<<705, 256, 0, stream>>>(pa, gum, edge, W1, b1, W2, W3, W4,
                                     D1, d1v, D2, D3, ws);
  k_diversity<<<256, 256, 0, stream>>>(times, d2v, d3v, ws);
  k_ab2<<<2048, 256, 0, stream>>>(times, ws + WS_U, ws + WS_V, ws + WS_W1ZT,
                                  ws + WS_W2T, b2, ws + WS_ABT, crx);
  k_mlp<<<512, 512, 0, stream>>>(times, ws + WS_U, ws + WS_V, ws + WS_W1ZT,
                                 ws + WS_W2T, ws + WS_ABT, crx,
                                 ws + WS_W3T, ws + WS_W4T, b2, b3, b4,
                                 ws + WS_DV, ws + WS_G, ws + WS_PEN, tau,
                                 ws + WS_CONS, (unsigned char*)ws + WSB_NXT8);
  k_phaseC<<<1, 1024, 0, stream>>>(ws, out);
  k_gather<<<512, 256, 0, stream>>>(ws, out);
}